// Round 4
// baseline (393.135 us; speedup 1.0000x reference)
//
#include <hip/hip_runtime.h>
#include <hip/hip_bf16.h>

#define L_SEQ 40
#define B_SZ  16
#define V_SZ  10000
#define V_PAD 10240
#define NPAIR 780
#define NROWP 784                 // 780 pairs + 1 init row + 3 pad "pairs"
#define M_ROWS (NROWP * B_SZ)     // 12544 rows = 49 strips of 256

typedef __attribute__((ext_vector_type(4))) float f32x4;
typedef __attribute__((ext_vector_type(4))) int   i32x4;
typedef __attribute__((ext_vector_type(8))) int   i32x8;

// ---------------------------------------------------------------------------
// float -> OCP e4m3fn. Prefer HW cvt; hand-rolled RNE fallback.
// ---------------------------------------------------------------------------
#if __has_builtin(__builtin_amdgcn_cvt_pk_fp8_f32)
__device__ __forceinline__ unsigned int pack4_fp8(float x0, float x1, float x2, float x3) {
    int lo = __builtin_amdgcn_cvt_pk_fp8_f32(x0, x1, 0, false);
    int full = __builtin_amdgcn_cvt_pk_fp8_f32(x2, x3, lo, true);
    return (unsigned int)full;
}
#else
__device__ __forceinline__ unsigned char f2e4m3(float f) {
    unsigned u = __float_as_uint(f);
    unsigned s = (u >> 24) & 0x80u;
    if ((u & 0x7FFFFFFFu) == 0) return (unsigned char)s;
    int E = (int)((u >> 23) & 0xFF) - 127 + 7;
    unsigned m = u & 0x7FFFFFu;
    if (E >= 16) return (unsigned char)(s | 0x7E);
    if (E >= 1) {
        unsigned keep = m >> 20, rest = m & 0xFFFFFu;
        keep += (rest > 0x80000u) || (rest == 0x80000u && (keep & 1));
        if (keep == 8) { keep = 0; E++; if (E >= 16) return (unsigned char)(s | 0x7E); }
        return (unsigned char)(s | (E << 3) | keep);
    }
    int shift = 1 - E;
    if (shift > 10) return (unsigned char)s;
    unsigned full = 0x800000u | m;
    unsigned sh = 20 + shift;
    unsigned keep = full >> sh, rem = full & ((1u << sh) - 1), half = 1u << (sh - 1);
    keep += (rem > half) || (rem == half && (keep & 1));
    if (keep >= 8) return (unsigned char)(s | (1 << 3));
    return (unsigned char)(s | keep);
}
__device__ __forceinline__ unsigned int pack4_fp8(float x0, float x1, float x2, float x3) {
    return (unsigned int)f2e4m3(x0) | ((unsigned int)f2e4m3(x1) << 8)
         | ((unsigned int)f2e4m3(x2) << 16) | ((unsigned int)f2e4m3(x3) << 24);
}
#endif

// 2^x via compiler-managed hardware exp (v_exp_f32 is base-2)
#if __has_builtin(__builtin_amdgcn_exp2f)
__device__ __forceinline__ float exp2_hw(float x) { return __builtin_amdgcn_exp2f(x); }
#else
__device__ __forceinline__ float exp2_hw(float x) { return __expf(x * 0.6931471805599453f); }
#endif

// Layout note: X and WbT are PLAIN row-major fp8 [row][k], 256 B per row.
// The MX-scaled MFMA (16x16x128) fragment is linear per lane: lane l holds
// row l&15, K-bytes (l>>4)*32 .. +31 — no byte permutation needed.

// ---------------------------------------------------------------------------
// K1: fused prep. [0,2560): transpose Ww2 -> WwT fp32 [10240,256] + WbT fp8
//     (linear row-major); [2560,2880): UV = h @ {Wt1,Ww1} halves; rest: zero
//     rowsum.
// ---------------------------------------------------------------------------
__global__ __launch_bounds__(256) void prep_kernel(
        const float* __restrict__ Ww2, float* __restrict__ WwT,
        unsigned char* __restrict__ WbT,
        const float* __restrict__ h, const float* __restrict__ Wt1,
        const float* __restrict__ Ww1, float* __restrict__ UV,
        float* __restrict__ rowsum) {
    const int bx = blockIdx.x;
    const int t = threadIdx.x;
    __shared__ float tile[32][33];
    __shared__ float hs[8 * 512];
    if (bx < 2560) {
        int v0 = (bx % 320) * 32;
        int K8 = bx / 320;           // k-tile index, k0 = K8*32
        int k0 = K8 * 32;
        int tx = t & 31, ty = t >> 5;   // 32 x 8
#pragma unroll
        for (int r = 0; r < 4; r++) {
            int k = k0 + ty + r * 8;
            int v = v0 + tx;
            tile[ty + r * 8][tx] = (v < V_SZ) ? Ww2[k * V_SZ + v] : 0.0f;   // tile[k][v]
        }
        __syncthreads();
        // fp32 transposed write
#pragma unroll
        for (int r = 0; r < 4; r++) {
            int vrow = ty + r * 8;
            WwT[(v0 + vrow) * 256 + (k0 + tx)] = tile[tx][vrow];
        }
        // fp8 write: thread -> (col v2, 4 consecutive k), linear layout
        int v2 = t >> 3;                 // 0..31
        int kq = 4 * (t & 7);            // local k base 0..28
        unsigned int pk = pack4_fp8(tile[kq][v2], tile[kq + 1][v2],
                                    tile[kq + 2][v2], tile[kq + 3][v2]);
        ((unsigned int*)WbT)[(v0 + v2) * 64 + K8 * 8 + (t & 7)] = pk;
    } else if (bx < 2880) {
        int ub = bx - 2560;
        int which = ub / 80;         // 0:Ut 1:Vt 2:Uw 3:Vw
        int m0 = (ub % 80) * 8;
        const float4* src = (const float4*)(h + (size_t)m0 * 512);
        float4* dst4 = (float4*)hs;
#pragma unroll
        for (int v = 0; v < 4; v++) dst4[v * 256 + t] = src[v * 256 + t];
        __syncthreads();
        const float* W = ((which < 2) ? Wt1 : Ww1) + ((which & 1) ? 512 * 256 : 0);
        float acc[8] = {};
        for (int f = 0; f < 512; f += 4) {
            float w0 = W[(f + 0) * 256 + t];
            float w1 = W[(f + 1) * 256 + t];
            float w2 = W[(f + 2) * 256 + t];
            float w3 = W[(f + 3) * 256 + t];
#pragma unroll
            for (int r = 0; r < 8; r++) {
                acc[r] += hs[r * 512 + f] * w0 + hs[r * 512 + f + 1] * w1
                        + hs[r * 512 + f + 2] * w2 + hs[r * 512 + f + 3] * w3;
            }
        }
        float* dst = UV + ((size_t)which * 640 + m0) * 256;
#pragma unroll
        for (int r = 0; r < 8; r++) dst[r * 256 + t] = acc[r];
    } else {
        int idx = (bx - 2880) * 256 + t;
        if (idx < M_ROWS) rowsum[idx] = 0.0f;
    }
}

// ---------------------------------------------------------------------------
// K2: per (pair,b) row: X = fp8(tanh(Uw[i]+Vw[j]+bw1)) linear row-major;
//     tlog/glog fp32 exact. One wave per row; p==780 is the init cell.
// ---------------------------------------------------------------------------
__global__ void build_rows(const float* __restrict__ UV,
                           const int* __restrict__ sentence,
                           const float* __restrict__ bt1,
                           const float* __restrict__ bw1,
                           const float* __restrict__ Wt2,
                           const float* __restrict__ bt2,
                           const float* __restrict__ WwT,
                           const float* __restrict__ bw2,
                           unsigned char* __restrict__ X,
                           float* __restrict__ tlog,
                           float* __restrict__ glog) {
    int w = blockIdx.x * 4 + (threadIdx.x >> 6);
    int lane = threadIdx.x & 63;
    int p = w >> 4, b = w & 15;
    int i = 0, j = 0;
    if (p < NPAIR) {
        int rem = p, len = L_SEQ - 1;
        while (rem >= len) { rem -= len; len--; i++; }
        j = i + 1 + rem;
    }
    int j1 = (j + 1 < L_SEQ) ? j + 1 : L_SEQ - 1;
    int tgt = sentence[j1 * B_SZ + b];
    const float4 ut = ((const float4*)(UV + 0 * 640 * 256 + (i * B_SZ + b) * 256))[lane];
    const float4 vt = ((const float4*)(UV + 1 * 640 * 256 + (j * B_SZ + b) * 256))[lane];
    const float4 uw = ((const float4*)(UV + 2 * 640 * 256 + (i * B_SZ + b) * 256))[lane];
    const float4 vw = ((const float4*)(UV + 3 * 640 * 256 + (j * B_SZ + b) * 256))[lane];
    const float4 bt = ((const float4*)bt1)[lane];
    const float4 bw = ((const float4*)bw1)[lane];
    const float4 w2 = ((const float4*)Wt2)[lane];
    const float4 wc = ((const float4*)(WwT + (size_t)tgt * 256))[lane];
    float xt0 = tanhf(ut.x + vt.x + bt.x), xt1 = tanhf(ut.y + vt.y + bt.y);
    float xt2 = tanhf(ut.z + vt.z + bt.z), xt3 = tanhf(ut.w + vt.w + bt.w);
    float xw0 = tanhf(uw.x + vw.x + bw.x), xw1 = tanhf(uw.y + vw.y + bw.y);
    float xw2 = tanhf(uw.z + vw.z + bw.z), xw3 = tanhf(uw.w + vw.w + bw.w);
    // linear: lane covers k = 4*lane .. 4*lane+3
    ((unsigned int*)X)[w * 64 + lane] = pack4_fp8(xw0, xw1, xw2, xw3);
    float td = xt0 * w2.x + xt1 * w2.y + xt2 * w2.z + xt3 * w2.w;
    float gd = xw0 * wc.x + xw1 * wc.y + xw2 * wc.z + xw3 * wc.w;
#pragma unroll
    for (int off = 32; off >= 1; off >>= 1) {
        td += __shfl_xor(td, off);
        gd += __shfl_xor(gd, off);
    }
    if (lane == 0) {
        tlog[w] = td + bt2[0];
        glog[w] = gd + bw2[tgt];
    }
}

// ---------------------------------------------------------------------------
// K3: MX-scaled fp8 GEMM (16x16x128, unit scales) + fused sum-exp.
// Occupancy-first restructure: block = 256 rows x 512 cols, 4 waves (one
// 64-row panel each), col-tile 64 -> Bs = 2 x 16 KB = 32 KB/block ->
// 4 blocks/CU -> 4 independent-block waves per SIMD (vs 2 before).
// Grid (20 col-groups, 49 strips) = 980 blocks <= 1024 resident slots:
// single round, no dispatch tail. Per iteration (64 cols): 16 ds_read_b128
// + 32 scaled MFMA + 64 exp2; one barrier. A panel (64 rows x K=256 fp8)
// in 64 VGPRs, loaded once. B double-buffered via global_load_lds w=16
// with XOR-granule swizzle (2-way max = free). Epilogue uses
// exp2(fma(acc, log2e, bias*log2e)) — 2 VALU ops/element.
// ---------------------------------------------------------------------------
__global__ __launch_bounds__(256, 4) void big_gemm(
        const unsigned char* __restrict__ X,
        const unsigned char* __restrict__ WbT,
        const float* __restrict__ bw2,
        float* __restrict__ rowsum) {
    __shared__ unsigned char Bs[2][64 * 256];    // 2 x 16 KB
    const int t = threadIdx.x;
    const int wid = t >> 6, lane = t & 63;
    const int l15 = lane & 15, l4 = lane >> 4;
    const int g = blockIdx.x;                    // col group: 512 cols
    const int row0 = blockIdx.y * 256 + wid * 64;

    auto dmaB = [&](int buf, int it) {
        const unsigned char* Bg = WbT + (size_t)(g * 512 + it * 64) * 256;
#pragma unroll
        for (int q = 0; q < 4; q++) {
            int base = (wid * 4 + q) * 1024;     // wave-uniform dest
            int F = base + lane * 16;            // this lane's dest byte
            int cc = F >> 8;                     // dest col within tile
            int s = (F >> 4) & 15;               // dest granule slot
            int srcg = s ^ (cc & 15);            // swizzled source granule
            __builtin_amdgcn_global_load_lds(
                (const __attribute__((address_space(1))) unsigned int*)(Bg + cc * 256 + (srcg << 4)),
                (__attribute__((address_space(3))) unsigned int*)(&Bs[buf][0] + base),
                16, 0, 0);
        }
    };

    dmaB(0, 0);

    // ---- A panel: 64 rows x K=256 in 64 VGPRs (linear, 32 B/lane/block)
    i32x8 apan[4][2];
    {
        const unsigned char* Ag = X + (size_t)row0 * 256;
#pragma unroll
        for (int mi = 0; mi < 4; mi++)
#pragma unroll
            for (int kb = 0; kb < 2; kb++)
                apan[mi][kb] = *(const i32x8*)(Ag + (mi * 16 + l15) * 256 + kb * 128 + l4 * 32);
    }
    __syncthreads();   // drains DMA for iter 0 too

    float PS[4][4] = {};
    const float L2E = 1.44269504088896340736f;

#pragma unroll 1
    for (int it = 0; it < 8; it++) {
        if (it < 7) dmaB((it + 1) & 1, it + 1);
        const unsigned char* Bb = &Bs[it & 1][0];
        f32x4 acc[4][4] = {};
#pragma unroll
        for (int kb = 0; kb < 2; kb++) {
            i32x8 b[4];
#pragma unroll
            for (int ni = 0; ni < 4; ni++) {
                int cc = ni * 16 + l15;          // wave covers all 64 cols
                int g0 = kb * 8 + l4 * 2;        // first 16-B granule of lane's 32 B
                i32x4 lo = *(const i32x4*)(Bb + cc * 256 + (((g0 + 0) ^ (cc & 15)) << 4));
                i32x4 hi = *(const i32x4*)(Bb + cc * 256 + (((g0 + 1) ^ (cc & 15)) << 4));
                i32x8 bv = {lo.x, lo.y, lo.z, lo.w, hi.x, hi.y, hi.z, hi.w};
                b[ni] = bv;
            }
#pragma unroll
            for (int mi = 0; mi < 4; mi++)
#pragma unroll
                for (int ni = 0; ni < 4; ni++)
                    acc[mi][ni] = __builtin_amdgcn_mfma_scale_f32_16x16x128_f8f6f4(
                        apan[mi][kb], b[ni], acc[mi][ni],
                        0, 0,                  // cbsz=fp8(e4m3), blgp=fp8(e4m3)
                        0, 0x7F7F7F7F,         // scale_a opsel, e8m0 unit scales
                        0, 0x7F7F7F7F);        // scale_b opsel, e8m0 unit scales
        }
        // ---- epilogue: exp2(acc*log2e + bias*log2e) into per-lane partials
#pragma unroll
        for (int ni = 0; ni < 4; ni++) {
            int col = g * 512 + it * 64 + ni * 16 + l15;
            float bL = (col < V_SZ) ? bw2[col] * L2E : -__builtin_inff();
#pragma unroll
            for (int mi = 0; mi < 4; mi++)
#pragma unroll
                for (int r = 0; r < 4; r++)
                    PS[mi][r] += exp2_hw(fmaf(acc[mi][ni][r], L2E, bL));
        }
        __syncthreads();
    }
    // ---- one butterfly + atomics per wave ----
#pragma unroll
    for (int mi = 0; mi < 4; mi++)
#pragma unroll
        for (int r = 0; r < 4; r++) {
            float v = PS[mi][r];
            v += __shfl_xor(v, 1); v += __shfl_xor(v, 2);
            v += __shfl_xor(v, 4); v += __shfl_xor(v, 8);
            if (l15 == 0)
                atomicAdd(&rowsum[row0 + mi * 16 + l4 * 4 + r], v);
        }
}

// ---------------------------------------------------------------------------
// K4: build tables in LDS + CKY DP. 16 blocks (one per batch), 1024 thr,
// 16 lanes per (i) cell parallelize the split loop.
// ---------------------------------------------------------------------------
__global__ __launch_bounds__(1024) void dp_kernel(const float* __restrict__ tlog,
                          const float* __restrict__ glog,
                          const float* __restrict__ rowsum,
                          float* __restrict__ out) {
    __shared__ float Tl[1600], SHWl[1600], REl[1600];
    const int t = threadIdx.x;
    const int b = blockIdx.x;
    const float NEGINF = -__builtin_inff();
    for (int idx = t; idx < 1600; idx += 1024) {
        Tl[idx] = NEGINF; SHWl[idx] = NEGINF; REl[idx] = NEGINF;
    }
    __syncthreads();
    for (int p = t; p < NPAIR; p += 1024) {
        int i = 0, rem = p, len = L_SEQ - 1;
        while (rem >= len) { rem -= len; len--; i++; }
        int j = i + 1 + rem;
        int row = p * 16 + b;
        float tl = tlog[row];
        float re_v = (tl >= 0.f) ? -log1pf(__expf(-tl)) : (tl - log1pf(__expf(tl)));
        float sh_v = (tl <= 0.f) ? -log1pf(__expf(tl)) : (-tl - log1pf(__expf(-tl)));
        float wlp = glog[row] - __logf(rowsum[row]);
        SHWl[i * 40 + j] = sh_v + wlp;
        REl[i * 40 + j] = re_v;
    }
    if (t == 0) {
        int row = NPAIR * 16 + b;           // init cell
        Tl[0 * 40 + 1] = glog[row] - __logf(rowsum[row]);
    }
    if (t >= 1 && t <= 38) Tl[t * 40 + t + 1] = 0.f;
    __syncthreads();
    const int tg = t >> 4, li = t & 15;
    for (int gap = 2; gap <= L_SEQ - 1; gap++) {
        int n_i = L_SEQ - gap;
        float m = NEGINF, s = 0.f;
        int i = tg, j = tg + gap;
        if (tg < n_i) {
            for (int k = i + 1 + li; k < j; k += 16) {
                float v = Tl[i * 40 + k] + Tl[k * 40 + j]
                        + SHWl[i * 40 + k] + REl[k * 40 + j];
                if (v > m) { s = s * __expf(m - v) + 1.f; m = v; }
                else s += __expf(v - m);
            }
        }
#pragma unroll
        for (int off = 1; off < 16; off <<= 1) {
            float mo = __shfl_xor(m, off), so = __shfl_xor(s, off);
            float M = fmaxf(m, mo);
            float sn = 0.f;
            if (m > NEGINF) sn += s * __expf(m - M);
            if (mo > NEGINF) sn += so * __expf(mo - M);
            m = M; s = sn;
        }
        if (tg < n_i && li == 0) Tl[i * 40 + j] = m + __logf(s);
        __syncthreads();
    }
    if (t == 0) out[b] = Tl[39];
}

// ---------------------------------------------------------------------------
extern "C" void kernel_launch(void* const* d_in, const int* in_sizes, int n_in,
                              void* d_out, int out_size, void* d_ws, size_t ws_size,
                              hipStream_t stream) {
    const float* h        = (const float*)d_in[0];
    const int*   sentence = (const int*)d_in[1];
    const float* Wt1      = (const float*)d_in[2];
    const float* bt1      = (const float*)d_in[3];
    const float* Wt2      = (const float*)d_in[4];
    const float* bt2      = (const float*)d_in[5];
    const float* Ww1      = (const float*)d_in[6];
    const float* bw1      = (const float*)d_in[7];
    const float* Ww2      = (const float*)d_in[8];
    const float* bw2      = (const float*)d_in[9];
    float* out = (float*)d_out;

    char* ws = (char*)d_ws;
    size_t off = 0;
    float* UV = (float*)(ws + off);                    off += 4ull * 640 * 256 * 4;
    unsigned char* X = (unsigned char*)(ws + off);     off += (size_t)M_ROWS * 256;
    unsigned char* WbT = (unsigned char*)(ws + off);   off += (size_t)V_PAD * 256;
    float* WwT = (float*)(ws + off);                   off += (size_t)V_PAD * 256 * 4;
    float* rowsum = (float*)(ws + off);                off += (size_t)M_ROWS * 4;
    float* tlog = (float*)(ws + off);                  off += (size_t)M_ROWS * 4;
    float* glog = (float*)(ws + off);                  off += (size_t)M_ROWS * 4;

    const int zero_blocks = (M_ROWS + 255) / 256;      // 49
    prep_kernel<<<2880 + zero_blocks, 256, 0, stream>>>(
        Ww2, WwT, WbT, h, Wt1, Ww1, UV, rowsum);
    build_rows<<<M_ROWS / 4, 256, 0, stream>>>(UV, sentence, bt1, bw1, Wt2, bt2,
                                               WwT, bw2, X, tlog, glog);
    big_gemm<<<dim3(20, 49), 256, 0, stream>>>(X, WbT, bw2, rowsum);
    dp_kernel<<<16, 1024, 0, stream>>>(tlog, glog, rowsum, out);
}

// Round 5
// 217.723 us; speedup vs baseline: 1.8057x; 1.8057x over previous
//
#include <hip/hip_runtime.h>
#include <hip/hip_bf16.h>

#define L_SEQ 40
#define B_SZ  16
#define V_SZ  10000
#define V_PAD 10240
#define NPAIR 780
#define NROWP 784                 // 780 pairs + 1 init row + 3 pad "pairs"
#define M_ROWS (NROWP * B_SZ)     // 12544 rows = 98 strips of 128

typedef __attribute__((ext_vector_type(4))) float f32x4;
typedef __attribute__((ext_vector_type(4))) int   i32x4;
typedef __attribute__((ext_vector_type(8))) int   i32x8;

// ---------------------------------------------------------------------------
// float -> OCP e4m3fn. Prefer HW cvt; hand-rolled RNE fallback.
// ---------------------------------------------------------------------------
#if __has_builtin(__builtin_amdgcn_cvt_pk_fp8_f32)
__device__ __forceinline__ unsigned int pack4_fp8(float x0, float x1, float x2, float x3) {
    int lo = __builtin_amdgcn_cvt_pk_fp8_f32(x0, x1, 0, false);
    int full = __builtin_amdgcn_cvt_pk_fp8_f32(x2, x3, lo, true);
    return (unsigned int)full;
}
#else
__device__ __forceinline__ unsigned char f2e4m3(float f) {
    unsigned u = __float_as_uint(f);
    unsigned s = (u >> 24) & 0x80u;
    if ((u & 0x7FFFFFFFu) == 0) return (unsigned char)s;
    int E = (int)((u >> 23) & 0xFF) - 127 + 7;
    unsigned m = u & 0x7FFFFFu;
    if (E >= 16) return (unsigned char)(s | 0x7E);
    if (E >= 1) {
        unsigned keep = m >> 20, rest = m & 0xFFFFFu;
        keep += (rest > 0x80000u) || (rest == 0x80000u && (keep & 1));
        if (keep == 8) { keep = 0; E++; if (E >= 16) return (unsigned char)(s | 0x7E); }
        return (unsigned char)(s | (E << 3) | keep);
    }
    int shift = 1 - E;
    if (shift > 10) return (unsigned char)s;
    unsigned full = 0x800000u | m;
    unsigned sh = 20 + shift;
    unsigned keep = full >> sh, rem = full & ((1u << sh) - 1), half = 1u << (sh - 1);
    keep += (rem > half) || (rem == half && (keep & 1));
    if (keep >= 8) return (unsigned char)(s | (1 << 3));
    return (unsigned char)(s | keep);
}
__device__ __forceinline__ unsigned int pack4_fp8(float x0, float x1, float x2, float x3) {
    return (unsigned int)f2e4m3(x0) | ((unsigned int)f2e4m3(x1) << 8)
         | ((unsigned int)f2e4m3(x2) << 16) | ((unsigned int)f2e4m3(x3) << 24);
}
#endif

// 2^x via compiler-managed hardware exp (v_exp_f32 is base-2)
#if __has_builtin(__builtin_amdgcn_exp2f)
__device__ __forceinline__ float exp2_hw(float x) { return __builtin_amdgcn_exp2f(x); }
#else
__device__ __forceinline__ float exp2_hw(float x) { return __expf(x * 0.6931471805599453f); }
#endif

// Layout note: X and WbT are PLAIN row-major fp8 [row][k], 256 B per row.
// The MX-scaled MFMA (16x16x128) fragment is linear per lane: lane l holds
// row l&15, K-bytes (l>>4)*32 .. +31 — no byte permutation needed.

// ---------------------------------------------------------------------------
// K1: fused prep. [0,2560): transpose Ww2 -> WwT fp32 [10240,256] + WbT fp8
//     (linear row-major); [2560,2880): UV = h @ {Wt1,Ww1} halves; rest: zero
//     rowsum.
// ---------------------------------------------------------------------------
__global__ __launch_bounds__(256) void prep_kernel(
        const float* __restrict__ Ww2, float* __restrict__ WwT,
        unsigned char* __restrict__ WbT,
        const float* __restrict__ h, const float* __restrict__ Wt1,
        const float* __restrict__ Ww1, float* __restrict__ UV,
        float* __restrict__ rowsum) {
    const int bx = blockIdx.x;
    const int t = threadIdx.x;
    __shared__ float tile[32][33];
    __shared__ float hs[8 * 512];
    if (bx < 2560) {
        int v0 = (bx % 320) * 32;
        int K8 = bx / 320;           // k-tile index, k0 = K8*32
        int k0 = K8 * 32;
        int tx = t & 31, ty = t >> 5;   // 32 x 8
#pragma unroll
        for (int r = 0; r < 4; r++) {
            int k = k0 + ty + r * 8;
            int v = v0 + tx;
            tile[ty + r * 8][tx] = (v < V_SZ) ? Ww2[k * V_SZ + v] : 0.0f;   // tile[k][v]
        }
        __syncthreads();
        // fp32 transposed write
#pragma unroll
        for (int r = 0; r < 4; r++) {
            int vrow = ty + r * 8;
            WwT[(v0 + vrow) * 256 + (k0 + tx)] = tile[tx][vrow];
        }
        // fp8 write: thread -> (col v2, 4 consecutive k), linear layout
        int v2 = t >> 3;                 // 0..31
        int kq = 4 * (t & 7);            // local k base 0..28
        unsigned int pk = pack4_fp8(tile[kq][v2], tile[kq + 1][v2],
                                    tile[kq + 2][v2], tile[kq + 3][v2]);
        ((unsigned int*)WbT)[(v0 + v2) * 64 + K8 * 8 + (t & 7)] = pk;
    } else if (bx < 2880) {
        int ub = bx - 2560;
        int which = ub / 80;         // 0:Ut 1:Vt 2:Uw 3:Vw
        int m0 = (ub % 80) * 8;
        const float4* src = (const float4*)(h + (size_t)m0 * 512);
        float4* dst4 = (float4*)hs;
#pragma unroll
        for (int v = 0; v < 4; v++) dst4[v * 256 + t] = src[v * 256 + t];
        __syncthreads();
        const float* W = ((which < 2) ? Wt1 : Ww1) + ((which & 1) ? 512 * 256 : 0);
        float acc[8] = {};
        for (int f = 0; f < 512; f += 4) {
            float w0 = W[(f + 0) * 256 + t];
            float w1 = W[(f + 1) * 256 + t];
            float w2 = W[(f + 2) * 256 + t];
            float w3 = W[(f + 3) * 256 + t];
#pragma unroll
            for (int r = 0; r < 8; r++) {
                acc[r] += hs[r * 512 + f] * w0 + hs[r * 512 + f + 1] * w1
                        + hs[r * 512 + f + 2] * w2 + hs[r * 512 + f + 3] * w3;
            }
        }
        float* dst = UV + ((size_t)which * 640 + m0) * 256;
#pragma unroll
        for (int r = 0; r < 8; r++) dst[r * 256 + t] = acc[r];
    } else {
        int idx = (bx - 2880) * 256 + t;
        if (idx < M_ROWS) rowsum[idx] = 0.0f;
    }
}

// ---------------------------------------------------------------------------
// K2: per (pair,b) row: X = fp8(tanh(Uw[i]+Vw[j]+bw1)) linear row-major;
//     tlog/glog fp32 exact. One wave per row; p==780 is the init cell.
// ---------------------------------------------------------------------------
__global__ void build_rows(const float* __restrict__ UV,
                           const int* __restrict__ sentence,
                           const float* __restrict__ bt1,
                           const float* __restrict__ bw1,
                           const float* __restrict__ Wt2,
                           const float* __restrict__ bt2,
                           const float* __restrict__ WwT,
                           const float* __restrict__ bw2,
                           unsigned char* __restrict__ X,
                           float* __restrict__ tlog,
                           float* __restrict__ glog) {
    int w = blockIdx.x * 4 + (threadIdx.x >> 6);
    int lane = threadIdx.x & 63;
    int p = w >> 4, b = w & 15;
    int i = 0, j = 0;
    if (p < NPAIR) {
        int rem = p, len = L_SEQ - 1;
        while (rem >= len) { rem -= len; len--; i++; }
        j = i + 1 + rem;
    }
    int j1 = (j + 1 < L_SEQ) ? j + 1 : L_SEQ - 1;
    int tgt = sentence[j1 * B_SZ + b];
    const float4 ut = ((const float4*)(UV + 0 * 640 * 256 + (i * B_SZ + b) * 256))[lane];
    const float4 vt = ((const float4*)(UV + 1 * 640 * 256 + (j * B_SZ + b) * 256))[lane];
    const float4 uw = ((const float4*)(UV + 2 * 640 * 256 + (i * B_SZ + b) * 256))[lane];
    const float4 vw = ((const float4*)(UV + 3 * 640 * 256 + (j * B_SZ + b) * 256))[lane];
    const float4 bt = ((const float4*)bt1)[lane];
    const float4 bw = ((const float4*)bw1)[lane];
    const float4 w2 = ((const float4*)Wt2)[lane];
    const float4 wc = ((const float4*)(WwT + (size_t)tgt * 256))[lane];
    float xt0 = tanhf(ut.x + vt.x + bt.x), xt1 = tanhf(ut.y + vt.y + bt.y);
    float xt2 = tanhf(ut.z + vt.z + bt.z), xt3 = tanhf(ut.w + vt.w + bt.w);
    float xw0 = tanhf(uw.x + vw.x + bw.x), xw1 = tanhf(uw.y + vw.y + bw.y);
    float xw2 = tanhf(uw.z + vw.z + bw.z), xw3 = tanhf(uw.w + vw.w + bw.w);
    // linear: lane covers k = 4*lane .. 4*lane+3
    ((unsigned int*)X)[w * 64 + lane] = pack4_fp8(xw0, xw1, xw2, xw3);
    float td = xt0 * w2.x + xt1 * w2.y + xt2 * w2.z + xt3 * w2.w;
    float gd = xw0 * wc.x + xw1 * wc.y + xw2 * wc.z + xw3 * wc.w;
#pragma unroll
    for (int off = 32; off >= 1; off >>= 1) {
        td += __shfl_xor(td, off);
        gd += __shfl_xor(gd, off);
    }
    if (lane == 0) {
        tlog[w] = td + bt2[0];
        glog[w] = gd + bw2[tgt];
    }
}

// ---------------------------------------------------------------------------
// K3: MX-scaled fp8 GEMM (16x16x128, unit scales) + fused sum-exp.
// Register-budget-correct occupancy design (round-4 lesson: 64x64 wave tile
// + A-in-reg needs ~190 regs and spills at a 128 cap -> 404 MB scratch).
// Wave tile = 32 rows x 64 cols: apan[2][2]=32 + acc[2][4]=32 + PS=8 +
// b(per-ni)=8..16 + addr ~ 110 regs < 128 -> true 4 waves/SIMD, no spill.
// Block = 128 rows x 64-col iteration, 4 waves; Bs = 2 x 16 KB = 32 KB.
// Grid (10 col-groups x 1024 cols, 98 strips) = 980 blocks <= 1024 slots:
// single dispatch round. Per iter/wave: 16 ds_read_b128 + 16 MFMA + 32 exp2;
// one barrier. B via global_load_lds w=16 + XOR-granule swizzle (2-way max).
// ---------------------------------------------------------------------------
__global__ __launch_bounds__(256, 4) void big_gemm(
        const unsigned char* __restrict__ X,
        const unsigned char* __restrict__ WbT,
        const float* __restrict__ bw2,
        float* __restrict__ rowsum) {
    __shared__ unsigned char Bs[2][64 * 256];    // 2 x 16 KB
    const int t = threadIdx.x;
    const int wid = t >> 6, lane = t & 63;
    const int l15 = lane & 15, l4 = lane >> 4;
    const int g = blockIdx.x;                    // col group: 1024 cols
    const int row0 = blockIdx.y * 128 + wid * 32;

    auto dmaB = [&](int buf, int it) {
        const unsigned char* Bg = WbT + (size_t)(g * 1024 + it * 64) * 256;
#pragma unroll
        for (int q = 0; q < 4; q++) {
            int base = (wid * 4 + q) * 1024;     // wave-uniform dest
            int F = base + lane * 16;            // this lane's dest byte
            int cc = F >> 8;                     // dest col within tile
            int s = (F >> 4) & 15;               // dest granule slot
            int srcg = s ^ (cc & 15);            // swizzled source granule
            __builtin_amdgcn_global_load_lds(
                (const __attribute__((address_space(1))) unsigned int*)(Bg + cc * 256 + (srcg << 4)),
                (__attribute__((address_space(3))) unsigned int*)(&Bs[buf][0] + base),
                16, 0, 0);
        }
    };

    dmaB(0, 0);

    // ---- A panel: 32 rows x K=256 in 32 VGPRs (linear, 32 B/lane/block)
    i32x8 apan[2][2];
    {
        const unsigned char* Ag = X + (size_t)row0 * 256;
#pragma unroll
        for (int mi = 0; mi < 2; mi++)
#pragma unroll
            for (int kb = 0; kb < 2; kb++)
                apan[mi][kb] = *(const i32x8*)(Ag + (mi * 16 + l15) * 256 + kb * 128 + l4 * 32);
    }
    __syncthreads();   // drains DMA for iter 0 too

    float PS[2][4] = {};
    const float L2E = 1.44269504088896340736f;

#pragma unroll 1
    for (int it = 0; it < 16; it++) {
        if (it < 15) dmaB((it + 1) & 1, it + 1);
        const unsigned char* Bb = &Bs[it & 1][0];
        f32x4 acc[2][4] = {};
#pragma unroll
        for (int kb = 0; kb < 2; kb++) {
#pragma unroll
            for (int ni = 0; ni < 4; ni++) {
                int cc = ni * 16 + l15;          // wave covers all 64 cols
                int g0 = kb * 8 + l4 * 2;        // first 16-B granule of lane's 32 B
                i32x4 lo = *(const i32x4*)(Bb + cc * 256 + (((g0 + 0) ^ (cc & 15)) << 4));
                i32x4 hi = *(const i32x4*)(Bb + cc * 256 + (((g0 + 1) ^ (cc & 15)) << 4));
                i32x8 bv = {lo.x, lo.y, lo.z, lo.w, hi.x, hi.y, hi.z, hi.w};
                acc[0][ni] = __builtin_amdgcn_mfma_scale_f32_16x16x128_f8f6f4(
                    apan[0][kb], bv, acc[0][ni], 0, 0,
                    0, 0x7F7F7F7F, 0, 0x7F7F7F7F);
                acc[1][ni] = __builtin_amdgcn_mfma_scale_f32_16x16x128_f8f6f4(
                    apan[1][kb], bv, acc[1][ni], 0, 0,
                    0, 0x7F7F7F7F, 0, 0x7F7F7F7F);
            }
        }
        // ---- epilogue: exp2(acc*log2e + bias*log2e) into per-lane partials
#pragma unroll
        for (int ni = 0; ni < 4; ni++) {
            int col = g * 1024 + it * 64 + ni * 16 + l15;
            float bL = (col < V_SZ) ? bw2[col] * L2E : -__builtin_inff();
#pragma unroll
            for (int mi = 0; mi < 2; mi++)
#pragma unroll
                for (int r = 0; r < 4; r++)
                    PS[mi][r] += exp2_hw(fmaf(acc[mi][ni][r], L2E, bL));
        }
        __syncthreads();
    }
    // ---- one butterfly + atomics per wave ----
#pragma unroll
    for (int mi = 0; mi < 2; mi++)
#pragma unroll
        for (int r = 0; r < 4; r++) {
            float v = PS[mi][r];
            v += __shfl_xor(v, 1); v += __shfl_xor(v, 2);
            v += __shfl_xor(v, 4); v += __shfl_xor(v, 8);
            if (l15 == 0)
                atomicAdd(&rowsum[row0 + mi * 16 + l4 * 4 + r], v);
        }
}

// ---------------------------------------------------------------------------
// K4: build tables in LDS + CKY DP. 16 blocks (one per batch), 1024 thr,
// 16 lanes per (i) cell parallelize the split loop.
// ---------------------------------------------------------------------------
__global__ __launch_bounds__(1024) void dp_kernel(const float* __restrict__ tlog,
                          const float* __restrict__ glog,
                          const float* __restrict__ rowsum,
                          float* __restrict__ out) {
    __shared__ float Tl[1600], SHWl[1600], REl[1600];
    const int t = threadIdx.x;
    const int b = blockIdx.x;
    const float NEGINF = -__builtin_inff();
    for (int idx = t; idx < 1600; idx += 1024) {
        Tl[idx] = NEGINF; SHWl[idx] = NEGINF; REl[idx] = NEGINF;
    }
    __syncthreads();
    for (int p = t; p < NPAIR; p += 1024) {
        int i = 0, rem = p, len = L_SEQ - 1;
        while (rem >= len) { rem -= len; len--; i++; }
        int j = i + 1 + rem;
        int row = p * 16 + b;
        float tl = tlog[row];
        float re_v = (tl >= 0.f) ? -log1pf(__expf(-tl)) : (tl - log1pf(__expf(tl)));
        float sh_v = (tl <= 0.f) ? -log1pf(__expf(tl)) : (-tl - log1pf(__expf(-tl)));
        float wlp = glog[row] - __logf(rowsum[row]);
        SHWl[i * 40 + j] = sh_v + wlp;
        REl[i * 40 + j] = re_v;
    }
    if (t == 0) {
        int row = NPAIR * 16 + b;           // init cell
        Tl[0 * 40 + 1] = glog[row] - __logf(rowsum[row]);
    }
    if (t >= 1 && t <= 38) Tl[t * 40 + t + 1] = 0.f;
    __syncthreads();
    const int tg = t >> 4, li = t & 15;
    for (int gap = 2; gap <= L_SEQ - 1; gap++) {
        int n_i = L_SEQ - gap;
        float m = NEGINF, s = 0.f;
        int i = tg, j = tg + gap;
        if (tg < n_i) {
            for (int k = i + 1 + li; k < j; k += 16) {
                float v = Tl[i * 40 + k] + Tl[k * 40 + j]
                        + SHWl[i * 40 + k] + REl[k * 40 + j];
                if (v > m) { s = s * __expf(m - v) + 1.f; m = v; }
                else s += __expf(v - m);
            }
        }
#pragma unroll
        for (int off = 1; off < 16; off <<= 1) {
            float mo = __shfl_xor(m, off), so = __shfl_xor(s, off);
            float M = fmaxf(m, mo);
            float sn = 0.f;
            if (m > NEGINF) sn += s * __expf(m - M);
            if (mo > NEGINF) sn += so * __expf(mo - M);
            m = M; s = sn;
        }
        if (tg < n_i && li == 0) Tl[i * 40 + j] = m + __logf(s);
        __syncthreads();
    }
    if (t == 0) out[b] = Tl[39];
}

// ---------------------------------------------------------------------------
extern "C" void kernel_launch(void* const* d_in, const int* in_sizes, int n_in,
                              void* d_out, int out_size, void* d_ws, size_t ws_size,
                              hipStream_t stream) {
    const float* h        = (const float*)d_in[0];
    const int*   sentence = (const int*)d_in[1];
    const float* Wt1      = (const float*)d_in[2];
    const float* bt1      = (const float*)d_in[3];
    const float* Wt2      = (const float*)d_in[4];
    const float* bt2      = (const float*)d_in[5];
    const float* Ww1      = (const float*)d_in[6];
    const float* bw1      = (const float*)d_in[7];
    const float* Ww2      = (const float*)d_in[8];
    const float* bw2      = (const float*)d_in[9];
    float* out = (float*)d_out;

    char* ws = (char*)d_ws;
    size_t off = 0;
    float* UV = (float*)(ws + off);                    off += 4ull * 640 * 256 * 4;
    unsigned char* X = (unsigned char*)(ws + off);     off += (size_t)M_ROWS * 256;
    unsigned char* WbT = (unsigned char*)(ws + off);   off += (size_t)V_PAD * 256;
    float* WwT = (float*)(ws + off);                   off += (size_t)V_PAD * 256 * 4;
    float* rowsum = (float*)(ws + off);                off += (size_t)M_ROWS * 4;
    float* tlog = (float*)(ws + off);                  off += (size_t)M_ROWS * 4;
    float* glog = (float*)(ws + off);                  off += (size_t)M_ROWS * 4;

    const int zero_blocks = (M_ROWS + 255) / 256;      // 49
    prep_kernel<<<2880 + zero_blocks, 256, 0, stream>>>(
        Ww2, WwT, WbT, h, Wt1, Ww1, UV, rowsum);
    build_rows<<<M_ROWS / 4, 256, 0, stream>>>(UV, sentence, bt1, bw1, Wt2, bt2,
                                               WwT, bw2, X, tlog, glog);
    big_gemm<<<dim3(10, 98), 256, 0, stream>>>(X, WbT, bw2, rowsum);
    dp_kernel<<<16, 1024, 0, stream>>>(tlog, glog, rowsum, out);
}

// Round 6
// 217.342 us; speedup vs baseline: 1.8088x; 1.0018x over previous
//
#include <hip/hip_runtime.h>
#include <hip/hip_bf16.h>

#define L_SEQ 40
#define B_SZ  16
#define V_SZ  10000
#define V_PAD 10240
#define NPAIR 780
#define NROWP 784                 // 780 pairs + 1 init row + 3 pad "pairs"
#define M_ROWS (NROWP * B_SZ)     // 12544 rows = 98 strips of 128

typedef __attribute__((ext_vector_type(4))) float f32x4;
typedef __attribute__((ext_vector_type(4))) int   i32x4;
typedef __attribute__((ext_vector_type(8))) int   i32x8;

// ---------------------------------------------------------------------------
// float -> OCP e4m3fn. Prefer HW cvt; hand-rolled RNE fallback.
// ---------------------------------------------------------------------------
#if __has_builtin(__builtin_amdgcn_cvt_pk_fp8_f32)
__device__ __forceinline__ unsigned int pack4_fp8(float x0, float x1, float x2, float x3) {
    int lo = __builtin_amdgcn_cvt_pk_fp8_f32(x0, x1, 0, false);
    int full = __builtin_amdgcn_cvt_pk_fp8_f32(x2, x3, lo, true);
    return (unsigned int)full;
}
#else
__device__ __forceinline__ unsigned char f2e4m3(float f) {
    unsigned u = __float_as_uint(f);
    unsigned s = (u >> 24) & 0x80u;
    if ((u & 0x7FFFFFFFu) == 0) return (unsigned char)s;
    int E = (int)((u >> 23) & 0xFF) - 127 + 7;
    unsigned m = u & 0x7FFFFFu;
    if (E >= 16) return (unsigned char)(s | 0x7E);
    if (E >= 1) {
        unsigned keep = m >> 20, rest = m & 0xFFFFFu;
        keep += (rest > 0x80000u) || (rest == 0x80000u && (keep & 1));
        if (keep == 8) { keep = 0; E++; if (E >= 16) return (unsigned char)(s | 0x7E); }
        return (unsigned char)(s | (E << 3) | keep);
    }
    int shift = 1 - E;
    if (shift > 10) return (unsigned char)s;
    unsigned full = 0x800000u | m;
    unsigned sh = 20 + shift;
    unsigned keep = full >> sh, rem = full & ((1u << sh) - 1), half = 1u << (sh - 1);
    keep += (rem > half) || (rem == half && (keep & 1));
    if (keep >= 8) return (unsigned char)(s | (1 << 3));
    return (unsigned char)(s | keep);
}
__device__ __forceinline__ unsigned int pack4_fp8(float x0, float x1, float x2, float x3) {
    return (unsigned int)f2e4m3(x0) | ((unsigned int)f2e4m3(x1) << 8)
         | ((unsigned int)f2e4m3(x2) << 16) | ((unsigned int)f2e4m3(x3) << 24);
}
#endif

// 2^x via compiler-managed hardware exp (v_exp_f32 is base-2)
#if __has_builtin(__builtin_amdgcn_exp2f)
__device__ __forceinline__ float exp2_hw(float x) { return __builtin_amdgcn_exp2f(x); }
#else
__device__ __forceinline__ float exp2_hw(float x) { return __expf(x * 0.6931471805599453f); }
#endif

#if __has_builtin(__builtin_amdgcn_rcpf)
__device__ __forceinline__ float rcp_hw(float x) { return __builtin_amdgcn_rcpf(x); }
#else
__device__ __forceinline__ float rcp_hw(float x) { return 1.0f / x; }
#endif

// tanh(x) = 1 - 2/(e^{2x}+1): exp2 + add + rcp + fma = 5 VALU ops vs ~30 for
// ocml tanhf. Exact at +/-inf saturation; |err| ~1e-6 (rcp is ~1 ulp).
__device__ __forceinline__ float fast_tanh(float x) {
    float e = exp2_hw(x * 2.885390081777926814f);   // 2*log2(e)
    return fmaf(-2.0f, rcp_hw(e + 1.0f), 1.0f);
}

// Layout note: X and WbT are PLAIN row-major fp8 [row][k], 256 B per row.
// The MX-scaled MFMA (16x16x128) fragment is linear per lane: lane l holds
// row l&15, K-bytes (l>>4)*32 .. +31 — no byte permutation needed.

// ---------------------------------------------------------------------------
// K1: fused prep. [0,2560): transpose Ww2 -> WwT fp32 [10240,256] + WbT fp8
//     (linear row-major); [2560,2880): UV = h @ {Wt1,Ww1} halves; rest: zero
//     rowsum.
// ---------------------------------------------------------------------------
__global__ __launch_bounds__(256) void prep_kernel(
        const float* __restrict__ Ww2, float* __restrict__ WwT,
        unsigned char* __restrict__ WbT,
        const float* __restrict__ h, const float* __restrict__ Wt1,
        const float* __restrict__ Ww1, float* __restrict__ UV,
        float* __restrict__ rowsum) {
    const int bx = blockIdx.x;
    const int t = threadIdx.x;
    __shared__ float tile[32][33];
    __shared__ float hs[8 * 512];
    if (bx < 2560) {
        int v0 = (bx % 320) * 32;
        int K8 = bx / 320;           // k-tile index, k0 = K8*32
        int k0 = K8 * 32;
        int tx = t & 31, ty = t >> 5;   // 32 x 8
#pragma unroll
        for (int r = 0; r < 4; r++) {
            int k = k0 + ty + r * 8;
            int v = v0 + tx;
            tile[ty + r * 8][tx] = (v < V_SZ) ? Ww2[k * V_SZ + v] : 0.0f;   // tile[k][v]
        }
        __syncthreads();
        // fp32 transposed write
#pragma unroll
        for (int r = 0; r < 4; r++) {
            int vrow = ty + r * 8;
            WwT[(v0 + vrow) * 256 + (k0 + tx)] = tile[tx][vrow];
        }
        // fp8 write: thread -> (col v2, 4 consecutive k), linear layout
        int v2 = t >> 3;                 // 0..31
        int kq = 4 * (t & 7);            // local k base 0..28
        unsigned int pk = pack4_fp8(tile[kq][v2], tile[kq + 1][v2],
                                    tile[kq + 2][v2], tile[kq + 3][v2]);
        ((unsigned int*)WbT)[(v0 + v2) * 64 + K8 * 8 + (t & 7)] = pk;
    } else if (bx < 2880) {
        int ub = bx - 2560;
        int which = ub / 80;         // 0:Ut 1:Vt 2:Uw 3:Vw
        int m0 = (ub % 80) * 8;
        const float4* src = (const float4*)(h + (size_t)m0 * 512);
        float4* dst4 = (float4*)hs;
#pragma unroll
        for (int v = 0; v < 4; v++) dst4[v * 256 + t] = src[v * 256 + t];
        __syncthreads();
        const float* W = ((which < 2) ? Wt1 : Ww1) + ((which & 1) ? 512 * 256 : 0);
        float acc[8] = {};
        for (int f = 0; f < 512; f += 4) {
            float w0 = W[(f + 0) * 256 + t];
            float w1 = W[(f + 1) * 256 + t];
            float w2 = W[(f + 2) * 256 + t];
            float w3 = W[(f + 3) * 256 + t];
#pragma unroll
            for (int r = 0; r < 8; r++) {
                acc[r] += hs[r * 512 + f] * w0 + hs[r * 512 + f + 1] * w1
                        + hs[r * 512 + f + 2] * w2 + hs[r * 512 + f + 3] * w3;
            }
        }
        float* dst = UV + ((size_t)which * 640 + m0) * 256;
#pragma unroll
        for (int r = 0; r < 8; r++) dst[r * 256 + t] = acc[r];
    } else {
        int idx = (bx - 2880) * 256 + t;
        if (idx < M_ROWS) rowsum[idx] = 0.0f;
    }
}

// ---------------------------------------------------------------------------
// K2: per (pair,b) row: X = fp8(tanh(Uw[i]+Vw[j]+bw1)) linear row-major;
//     tlog/glog fp32 exact. One wave per row; p==780 is the init cell.
// fast_tanh (5 ops) replaces ocml tanhf (~30 ops incl divide).
// ---------------------------------------------------------------------------
__global__ void build_rows(const float* __restrict__ UV,
                           const int* __restrict__ sentence,
                           const float* __restrict__ bt1,
                           const float* __restrict__ bw1,
                           const float* __restrict__ Wt2,
                           const float* __restrict__ bt2,
                           const float* __restrict__ WwT,
                           const float* __restrict__ bw2,
                           unsigned char* __restrict__ X,
                           float* __restrict__ tlog,
                           float* __restrict__ glog) {
    int w = blockIdx.x * 4 + (threadIdx.x >> 6);
    int lane = threadIdx.x & 63;
    int p = w >> 4, b = w & 15;
    int i = 0, j = 0;
    if (p < NPAIR) {
        int rem = p, len = L_SEQ - 1;
        while (rem >= len) { rem -= len; len--; i++; }
        j = i + 1 + rem;
    }
    int j1 = (j + 1 < L_SEQ) ? j + 1 : L_SEQ - 1;
    int tgt = sentence[j1 * B_SZ + b];
    const float4 ut = ((const float4*)(UV + 0 * 640 * 256 + (i * B_SZ + b) * 256))[lane];
    const float4 vt = ((const float4*)(UV + 1 * 640 * 256 + (j * B_SZ + b) * 256))[lane];
    const float4 uw = ((const float4*)(UV + 2 * 640 * 256 + (i * B_SZ + b) * 256))[lane];
    const float4 vw = ((const float4*)(UV + 3 * 640 * 256 + (j * B_SZ + b) * 256))[lane];
    const float4 bt = ((const float4*)bt1)[lane];
    const float4 bw = ((const float4*)bw1)[lane];
    const float4 w2 = ((const float4*)Wt2)[lane];
    const float4 wc = ((const float4*)(WwT + (size_t)tgt * 256))[lane];
    float xt0 = fast_tanh(ut.x + vt.x + bt.x), xt1 = fast_tanh(ut.y + vt.y + bt.y);
    float xt2 = fast_tanh(ut.z + vt.z + bt.z), xt3 = fast_tanh(ut.w + vt.w + bt.w);
    float xw0 = fast_tanh(uw.x + vw.x + bw.x), xw1 = fast_tanh(uw.y + vw.y + bw.y);
    float xw2 = fast_tanh(uw.z + vw.z + bw.z), xw3 = fast_tanh(uw.w + vw.w + bw.w);
    // linear: lane covers k = 4*lane .. 4*lane+3
    ((unsigned int*)X)[w * 64 + lane] = pack4_fp8(xw0, xw1, xw2, xw3);
    float td = xt0 * w2.x + xt1 * w2.y + xt2 * w2.z + xt3 * w2.w;
    float gd = xw0 * wc.x + xw1 * wc.y + xw2 * wc.z + xw3 * wc.w;
#pragma unroll
    for (int off = 32; off >= 1; off >>= 1) {
        td += __shfl_xor(td, off);
        gd += __shfl_xor(gd, off);
    }
    if (lane == 0) {
        tlog[w] = td + bt2[0];
        glog[w] = gd + bw2[tgt];
    }
}

// ---------------------------------------------------------------------------
// K3: MX-scaled fp8 GEMM (16x16x128, unit scales) + fused sum-exp.
// Round-6: counted-vmcnt 3-stage pipeline (T3/T4). Per iteration:
//   [s_waitcnt vmcnt(4); s_barrier]  <- tile it guaranteed (only the 4 newest
//                                       loads, tile it+1, may remain in flight)
//   issue DMA tile it+2               <- WAR-safe: barrier proved all waves
//                                       consumed tile it-1 (same buffer)
//   ds_read + MFMA + exp tile it
// Never drains vmcnt to 0 in the loop (round-5 lesson: the __syncthreads
// drain serialized DMA completion against compute; occupancy 15->37% gave
// zero speedup). 3 x 16 KB buffers = 48 KB -> 3 blocks/CU. Wave tile
// 32 rows x 64 cols (fits 128-reg budget, round-4 lesson). Grid (8 groups
// x 1280 cols, 98 strips) = 784 blocks ~ 768 resident.
// ---------------------------------------------------------------------------
__global__ __launch_bounds__(256, 3) void big_gemm(
        const unsigned char* __restrict__ X,
        const unsigned char* __restrict__ WbT,
        const float* __restrict__ bw2,
        float* __restrict__ rowsum) {
    __shared__ unsigned char Bs[3][64 * 256];    // 3 x 16 KB
    const int t = threadIdx.x;
    const int wid = t >> 6, lane = t & 63;
    const int l15 = lane & 15, l4 = lane >> 4;
    const int g = blockIdx.x;                    // col group: 1280 cols
    const int row0 = blockIdx.y * 128 + wid * 32;
    const int NIT = 20;

    auto dmaB = [&](int buf, int it) {
        const unsigned char* Bg = WbT + (size_t)(g * 1280 + it * 64) * 256;
#pragma unroll
        for (int q = 0; q < 4; q++) {
            int off = (wid * 4 + q) * 1024;      // wave-uniform dest (in tile)
            int F = off + lane * 16;             // this lane's dest byte
            int cc = F >> 8;                     // dest col within tile
            int s = (F >> 4) & 15;               // dest granule slot
            int srcg = s ^ (cc & 15);            // swizzled source granule
            __builtin_amdgcn_global_load_lds(
                (const __attribute__((address_space(1))) unsigned int*)(Bg + cc * 256 + (srcg << 4)),
                (__attribute__((address_space(3))) unsigned int*)(&Bs[buf][0] + off),
                16, 0, 0);
        }
    };

    // ---- A panel: 32 rows x K=256 in 32 VGPRs (linear, 32 B/lane/block)
    i32x8 apan[2][2];
    {
        const unsigned char* Ag = X + (size_t)row0 * 256;
#pragma unroll
        for (int mi = 0; mi < 2; mi++)
#pragma unroll
            for (int kb = 0; kb < 2; kb++)
                apan[mi][kb] = *(const i32x8*)(Ag + (mi * 16 + l15) * 256 + kb * 128 + l4 * 32);
    }
    // prologue: two tiles in flight (issued AFTER A loads, so vmcnt(4) at
    // iter 0 also drains the A loads)
    dmaB(0, 0);
    dmaB(1, 1);

    float PS[2][4] = {};
    const float L2E = 1.44269504088896340736f;
    int cur = 0, pre = 2;

#pragma unroll 1
    for (int it = 0; it < NIT; it++) {
        // tile `it` ready: only tile it+1's 4 loads may stay outstanding.
        if (it < NIT - 1) {
            asm volatile("s_waitcnt vmcnt(4)\n\ts_barrier" ::: "memory");
        } else {
            asm volatile("s_waitcnt vmcnt(0)\n\ts_barrier" ::: "memory");
        }
        if (it + 2 < NIT) dmaB(pre, it + 2);
        const unsigned char* Bb = &Bs[cur][0];
        f32x4 acc[2][4] = {};
#pragma unroll
        for (int kb = 0; kb < 2; kb++) {
#pragma unroll
            for (int ni = 0; ni < 4; ni++) {
                int cc = ni * 16 + l15;          // wave covers all 64 cols
                int g0 = kb * 8 + l4 * 2;        // first 16-B granule of lane's 32 B
                i32x4 lo = *(const i32x4*)(Bb + cc * 256 + (((g0 + 0) ^ (cc & 15)) << 4));
                i32x4 hi = *(const i32x4*)(Bb + cc * 256 + (((g0 + 1) ^ (cc & 15)) << 4));
                i32x8 bv = {lo.x, lo.y, lo.z, lo.w, hi.x, hi.y, hi.z, hi.w};
                acc[0][ni] = __builtin_amdgcn_mfma_scale_f32_16x16x128_f8f6f4(
                    apan[0][kb], bv, acc[0][ni], 0, 0,
                    0, 0x7F7F7F7F, 0, 0x7F7F7F7F);
                acc[1][ni] = __builtin_amdgcn_mfma_scale_f32_16x16x128_f8f6f4(
                    apan[1][kb], bv, acc[1][ni], 0, 0,
                    0, 0x7F7F7F7F, 0, 0x7F7F7F7F);
            }
        }
        // ---- epilogue: exp2(acc*log2e + bias*log2e) into per-lane partials
#pragma unroll
        for (int ni = 0; ni < 4; ni++) {
            int col = g * 1280 + it * 64 + ni * 16 + l15;
            float bL = (col < V_SZ) ? bw2[col] * L2E : -__builtin_inff();
#pragma unroll
            for (int mi = 0; mi < 2; mi++)
#pragma unroll
                for (int r = 0; r < 4; r++)
                    PS[mi][r] += exp2_hw(fmaf(acc[mi][ni][r], L2E, bL));
        }
        cur = (cur == 2) ? 0 : cur + 1;
        pre = (pre == 2) ? 0 : pre + 1;
    }
    // ---- one butterfly + atomics per wave ----
#pragma unroll
    for (int mi = 0; mi < 2; mi++)
#pragma unroll
        for (int r = 0; r < 4; r++) {
            float v = PS[mi][r];
            v += __shfl_xor(v, 1); v += __shfl_xor(v, 2);
            v += __shfl_xor(v, 4); v += __shfl_xor(v, 8);
            if (l15 == 0)
                atomicAdd(&rowsum[row0 + mi * 16 + l4 * 4 + r], v);
        }
}

// ---------------------------------------------------------------------------
// K4: build tables in LDS + CKY DP. 16 blocks (one per batch), 1024 thr,
// 16 lanes per (i) cell parallelize the split loop.
// ---------------------------------------------------------------------------
__global__ __launch_bounds__(1024) void dp_kernel(const float* __restrict__ tlog,
                          const float* __restrict__ glog,
                          const float* __restrict__ rowsum,
                          float* __restrict__ out) {
    __shared__ float Tl[1600], SHWl[1600], REl[1600];
    const int t = threadIdx.x;
    const int b = blockIdx.x;
    const float NEGINF = -__builtin_inff();
    for (int idx = t; idx < 1600; idx += 1024) {
        Tl[idx] = NEGINF; SHWl[idx] = NEGINF; REl[idx] = NEGINF;
    }
    __syncthreads();
    for (int p = t; p < NPAIR; p += 1024) {
        int i = 0, rem = p, len = L_SEQ - 1;
        while (rem >= len) { rem -= len; len--; i++; }
        int j = i + 1 + rem;
        int row = p * 16 + b;
        float tl = tlog[row];
        float re_v = (tl >= 0.f) ? -log1pf(__expf(-tl)) : (tl - log1pf(__expf(tl)));
        float sh_v = (tl <= 0.f) ? -log1pf(__expf(tl)) : (-tl - log1pf(__expf(-tl)));
        float wlp = glog[row] - __logf(rowsum[row]);
        SHWl[i * 40 + j] = sh_v + wlp;
        REl[i * 40 + j] = re_v;
    }
    if (t == 0) {
        int row = NPAIR * 16 + b;           // init cell
        Tl[0 * 40 + 1] = glog[row] - __logf(rowsum[row]);
    }
    if (t >= 1 && t <= 38) Tl[t * 40 + t + 1] = 0.f;
    __syncthreads();
    const int tg = t >> 4, li = t & 15;
    for (int gap = 2; gap <= L_SEQ - 1; gap++) {
        int n_i = L_SEQ - gap;
        float m = NEGINF, s = 0.f;
        int i = tg, j = tg + gap;
        if (tg < n_i) {
            for (int k = i + 1 + li; k < j; k += 16) {
                float v = Tl[i * 40 + k] + Tl[k * 40 + j]
                        + SHWl[i * 40 + k] + REl[k * 40 + j];
                if (v > m) { s = s * __expf(m - v) + 1.f; m = v; }
                else s += __expf(v - m);
            }
        }
#pragma unroll
        for (int off = 1; off < 16; off <<= 1) {
            float mo = __shfl_xor(m, off), so = __shfl_xor(s, off);
            float M = fmaxf(m, mo);
            float sn = 0.f;
            if (m > NEGINF) sn += s * __expf(m - M);
            if (mo > NEGINF) sn += so * __expf(mo - M);
            m = M; s = sn;
        }
        if (tg < n_i && li == 0) Tl[i * 40 + j] = m + __logf(s);
        __syncthreads();
    }
    if (t == 0) out[b] = Tl[39];
}

// ---------------------------------------------------------------------------
extern "C" void kernel_launch(void* const* d_in, const int* in_sizes, int n_in,
                              void* d_out, int out_size, void* d_ws, size_t ws_size,
                              hipStream_t stream) {
    const float* h        = (const float*)d_in[0];
    const int*   sentence = (const int*)d_in[1];
    const float* Wt1      = (const float*)d_in[2];
    const float* bt1      = (const float*)d_in[3];
    const float* Wt2      = (const float*)d_in[4];
    const float* bt2      = (const float*)d_in[5];
    const float* Ww1      = (const float*)d_in[6];
    const float* bw1      = (const float*)d_in[7];
    const float* Ww2      = (const float*)d_in[8];
    const float* bw2      = (const float*)d_in[9];
    float* out = (float*)d_out;

    char* ws = (char*)d_ws;
    size_t off = 0;
    float* UV = (float*)(ws + off);                    off += 4ull * 640 * 256 * 4;
    unsigned char* X = (unsigned char*)(ws + off);     off += (size_t)M_ROWS * 256;
    unsigned char* WbT = (unsigned char*)(ws + off);   off += (size_t)V_PAD * 256;
    float* WwT = (float*)(ws + off);                   off += (size_t)V_PAD * 256 * 4;
    float* rowsum = (float*)(ws + off);                off += (size_t)M_ROWS * 4;
    float* tlog = (float*)(ws + off);                  off += (size_t)M_ROWS * 4;
    float* glog = (float*)(ws + off);                  off += (size_t)M_ROWS * 4;

    const int zero_blocks = (M_ROWS + 255) / 256;      // 49
    prep_kernel<<<2880 + zero_blocks, 256, 0, stream>>>(
        Ww2, WwT, WbT, h, Wt1, Ww1, UV, rowsum);
    build_rows<<<M_ROWS / 4, 256, 0, stream>>>(UV, sentence, bt1, bw1, Wt2, bt2,
                                               WwT, bw2, X, tlog, glog);
    big_gemm<<<dim3(8, 98), 256, 0, stream>>>(X, WbT, bw2, rowsum);
    dp_kernel<<<16, 1024, 0, stream>>>(tlog, glog, rowsum, out);
}

// Round 7
// 209.183 us; speedup vs baseline: 1.8794x; 1.0390x over previous
//
#include <hip/hip_runtime.h>
#include <hip/hip_bf16.h>

#define L_SEQ 40
#define B_SZ  16
#define V_SZ  10000
#define V_PAD 10240
#define NPAIR 780
#define NROWP 784                 // 780 pairs + 1 init row + 3 pad "pairs"
#define M_ROWS (NROWP * B_SZ)     // 12544 rows = 98 strips of 128

typedef __attribute__((ext_vector_type(4))) float f32x4;
typedef __attribute__((ext_vector_type(4))) int   i32x4;
typedef __attribute__((ext_vector_type(8))) int   i32x8;

// ---------------------------------------------------------------------------
// float -> OCP e4m3fn. Prefer HW cvt; hand-rolled RNE fallback.
// ---------------------------------------------------------------------------
#if __has_builtin(__builtin_amdgcn_cvt_pk_fp8_f32)
__device__ __forceinline__ unsigned int pack4_fp8(float x0, float x1, float x2, float x3) {
    int lo = __builtin_amdgcn_cvt_pk_fp8_f32(x0, x1, 0, false);
    int full = __builtin_amdgcn_cvt_pk_fp8_f32(x2, x3, lo, true);
    return (unsigned int)full;
}
#else
__device__ __forceinline__ unsigned char f2e4m3(float f) {
    unsigned u = __float_as_uint(f);
    unsigned s = (u >> 24) & 0x80u;
    if ((u & 0x7FFFFFFFu) == 0) return (unsigned char)s;
    int E = (int)((u >> 23) & 0xFF) - 127 + 7;
    unsigned m = u & 0x7FFFFFu;
    if (E >= 16) return (unsigned char)(s | 0x7E);
    if (E >= 1) {
        unsigned keep = m >> 20, rest = m & 0xFFFFFu;
        keep += (rest > 0x80000u) || (rest == 0x80000u && (keep & 1));
        if (keep == 8) { keep = 0; E++; if (E >= 16) return (unsigned char)(s | 0x7E); }
        return (unsigned char)(s | (E << 3) | keep);
    }
    int shift = 1 - E;
    if (shift > 10) return (unsigned char)s;
    unsigned full = 0x800000u | m;
    unsigned sh = 20 + shift;
    unsigned keep = full >> sh, rem = full & ((1u << sh) - 1), half = 1u << (sh - 1);
    keep += (rem > half) || (rem == half && (keep & 1));
    if (keep >= 8) return (unsigned char)(s | (1 << 3));
    return (unsigned char)(s | keep);
}
__device__ __forceinline__ unsigned int pack4_fp8(float x0, float x1, float x2, float x3) {
    return (unsigned int)f2e4m3(x0) | ((unsigned int)f2e4m3(x1) << 8)
         | ((unsigned int)f2e4m3(x2) << 16) | ((unsigned int)f2e4m3(x3) << 24);
}
#endif

// 2^x via compiler-managed hardware exp (v_exp_f32 is base-2)
#if __has_builtin(__builtin_amdgcn_exp2f)
__device__ __forceinline__ float exp2_hw(float x) { return __builtin_amdgcn_exp2f(x); }
#else
__device__ __forceinline__ float exp2_hw(float x) { return __expf(x * 0.6931471805599453f); }
#endif

#if __has_builtin(__builtin_amdgcn_rcpf)
__device__ __forceinline__ float rcp_hw(float x) { return __builtin_amdgcn_rcpf(x); }
#else
__device__ __forceinline__ float rcp_hw(float x) { return 1.0f / x; }
#endif

// tanh(x) = 1 - 2/(e^{2x}+1): exp2 + add + rcp + fma = 5 VALU ops vs ~30 for
// ocml tanhf. Exact at +/-inf saturation; |err| ~1e-6 (rcp is ~1 ulp).
__device__ __forceinline__ float fast_tanh(float x) {
    float e = exp2_hw(x * 2.885390081777926814f);   // 2*log2(e)
    return fmaf(-2.0f, rcp_hw(e + 1.0f), 1.0f);
}

// Layout note: X and WbT are PLAIN row-major fp8 [row][k], 256 B per row.
// The MX-scaled MFMA (16x16x128) fragment is linear per lane: lane l holds
// row l&15, K-bytes (l>>4)*32 .. +31 — no byte permutation needed.

// ---------------------------------------------------------------------------
// K1: fused prep. [0,2560): transpose Ww2 -> WwT fp32 [10240,256] + WbT fp8
//     (linear row-major); [2560,2880): UV = h @ {Wt1,Ww1} halves; rest: zero
//     rowsum.
// ---------------------------------------------------------------------------
__global__ __launch_bounds__(256) void prep_kernel(
        const float* __restrict__ Ww2, float* __restrict__ WwT,
        unsigned char* __restrict__ WbT,
        const float* __restrict__ h, const float* __restrict__ Wt1,
        const float* __restrict__ Ww1, float* __restrict__ UV,
        float* __restrict__ rowsum) {
    const int bx = blockIdx.x;
    const int t = threadIdx.x;
    __shared__ float tile[32][33];
    __shared__ float hs[8 * 512];
    if (bx < 2560) {
        int v0 = (bx % 320) * 32;
        int K8 = bx / 320;           // k-tile index, k0 = K8*32
        int k0 = K8 * 32;
        int tx = t & 31, ty = t >> 5;   // 32 x 8
#pragma unroll
        for (int r = 0; r < 4; r++) {
            int k = k0 + ty + r * 8;
            int v = v0 + tx;
            tile[ty + r * 8][tx] = (v < V_SZ) ? Ww2[k * V_SZ + v] : 0.0f;   // tile[k][v]
        }
        __syncthreads();
        // fp32 transposed write
#pragma unroll
        for (int r = 0; r < 4; r++) {
            int vrow = ty + r * 8;
            WwT[(v0 + vrow) * 256 + (k0 + tx)] = tile[tx][vrow];
        }
        // fp8 write: thread -> (col v2, 4 consecutive k), linear layout
        int v2 = t >> 3;                 // 0..31
        int kq = 4 * (t & 7);            // local k base 0..28
        unsigned int pk = pack4_fp8(tile[kq][v2], tile[kq + 1][v2],
                                    tile[kq + 2][v2], tile[kq + 3][v2]);
        ((unsigned int*)WbT)[(v0 + v2) * 64 + K8 * 8 + (t & 7)] = pk;
    } else if (bx < 2880) {
        int ub = bx - 2560;
        int which = ub / 80;         // 0:Ut 1:Vt 2:Uw 3:Vw
        int m0 = (ub % 80) * 8;
        const float4* src = (const float4*)(h + (size_t)m0 * 512);
        float4* dst4 = (float4*)hs;
#pragma unroll
        for (int v = 0; v < 4; v++) dst4[v * 256 + t] = src[v * 256 + t];
        __syncthreads();
        const float* W = ((which < 2) ? Wt1 : Ww1) + ((which & 1) ? 512 * 256 : 0);
        float acc[8] = {};
        for (int f = 0; f < 512; f += 4) {
            float w0 = W[(f + 0) * 256 + t];
            float w1 = W[(f + 1) * 256 + t];
            float w2 = W[(f + 2) * 256 + t];
            float w3 = W[(f + 3) * 256 + t];
#pragma unroll
            for (int r = 0; r < 8; r++) {
                acc[r] += hs[r * 512 + f] * w0 + hs[r * 512 + f + 1] * w1
                        + hs[r * 512 + f + 2] * w2 + hs[r * 512 + f + 3] * w3;
            }
        }
        float* dst = UV + ((size_t)which * 640 + m0) * 256;
#pragma unroll
        for (int r = 0; r < 8; r++) dst[r * 256 + t] = acc[r];
    } else {
        int idx = (bx - 2880) * 256 + t;
        if (idx < M_ROWS) rowsum[idx] = 0.0f;
    }
}

// ---------------------------------------------------------------------------
// K2: per (pair,b) row: X = fp8(tanh(Uw[i]+Vw[j]+bw1)) linear row-major;
//     tlog/glog fp32 exact. One wave per row; p==780 is the init cell.
// ---------------------------------------------------------------------------
__global__ void build_rows(const float* __restrict__ UV,
                           const int* __restrict__ sentence,
                           const float* __restrict__ bt1,
                           const float* __restrict__ bw1,
                           const float* __restrict__ Wt2,
                           const float* __restrict__ bt2,
                           const float* __restrict__ WwT,
                           const float* __restrict__ bw2,
                           unsigned char* __restrict__ X,
                           float* __restrict__ tlog,
                           float* __restrict__ glog) {
    int w = blockIdx.x * 4 + (threadIdx.x >> 6);
    int lane = threadIdx.x & 63;
    int p = w >> 4, b = w & 15;
    int i = 0, j = 0;
    if (p < NPAIR) {
        int rem = p, len = L_SEQ - 1;
        while (rem >= len) { rem -= len; len--; i++; }
        j = i + 1 + rem;
    }
    int j1 = (j + 1 < L_SEQ) ? j + 1 : L_SEQ - 1;
    int tgt = sentence[j1 * B_SZ + b];
    const float4 ut = ((const float4*)(UV + 0 * 640 * 256 + (i * B_SZ + b) * 256))[lane];
    const float4 vt = ((const float4*)(UV + 1 * 640 * 256 + (j * B_SZ + b) * 256))[lane];
    const float4 uw = ((const float4*)(UV + 2 * 640 * 256 + (i * B_SZ + b) * 256))[lane];
    const float4 vw = ((const float4*)(UV + 3 * 640 * 256 + (j * B_SZ + b) * 256))[lane];
    const float4 bt = ((const float4*)bt1)[lane];
    const float4 bw = ((const float4*)bw1)[lane];
    const float4 w2 = ((const float4*)Wt2)[lane];
    const float4 wc = ((const float4*)(WwT + (size_t)tgt * 256))[lane];
    float xt0 = fast_tanh(ut.x + vt.x + bt.x), xt1 = fast_tanh(ut.y + vt.y + bt.y);
    float xt2 = fast_tanh(ut.z + vt.z + bt.z), xt3 = fast_tanh(ut.w + vt.w + bt.w);
    float xw0 = fast_tanh(uw.x + vw.x + bw.x), xw1 = fast_tanh(uw.y + vw.y + bw.y);
    float xw2 = fast_tanh(uw.z + vw.z + bw.z), xw3 = fast_tanh(uw.w + vw.w + bw.w);
    // linear: lane covers k = 4*lane .. 4*lane+3
    ((unsigned int*)X)[w * 64 + lane] = pack4_fp8(xw0, xw1, xw2, xw3);
    float td = xt0 * w2.x + xt1 * w2.y + xt2 * w2.z + xt3 * w2.w;
    float gd = xw0 * wc.x + xw1 * wc.y + xw2 * wc.z + xw3 * wc.w;
#pragma unroll
    for (int off = 32; off >= 1; off >>= 1) {
        td += __shfl_xor(td, off);
        gd += __shfl_xor(gd, off);
    }
    if (lane == 0) {
        tlog[w] = td + bt2[0];
        glog[w] = gd + bw2[tgt];
    }
}

// ---------------------------------------------------------------------------
// K3: MX-scaled fp8 GEMM (16x16x128, unit scales) + fused sum-exp.
// Round-7 fixes, from the vmcnt in-order-retirement insight:
//  (1) NO VMEM in the loop except the DMA. Round-6's epilogue bw2 loads were
//      issued AFTER the DMA; waiting on them implied draining both in-flight
//      tiles (vmcnt retires in order) -> the counted-vmcnt pipeline never ran.
//      bw2*log2e is now staged in LDS once (5 KB).
//  (2) Quarter-granularity register pipeline for B: each 64-col tile = 4
//      quarters (4 ds_read_b128 + 4 MFMA); quarter Q+1's reads issue before
//      Q's MFMAs (br0/br1 double buffer); q3 slot prefetches next tile's q0
//      (safe: DMA issued before vmcnt(4), so tile it+1 is proven complete).
//  (3) 16 swizzled LDS offsets hoisted to registers.
// 3 x 16 KB buffers + 5 KB bias = 53.25 KB -> 3 blocks/CU; ~150 VGPR < 170.
// ---------------------------------------------------------------------------
#define RDQ(BASE, Q, BR) \
    BR[0] = *(const i32x4*)((BASE) + offs[(Q)*4+0]); \
    BR[1] = *(const i32x4*)((BASE) + offs[(Q)*4+1]); \
    BR[2] = *(const i32x4*)((BASE) + offs[(Q)*4+2]); \
    BR[3] = *(const i32x4*)((BASE) + offs[(Q)*4+3]);

#define MFQ(Q, BR) { \
    i32x8 bv0_ = __builtin_shufflevector(BR[0], BR[1], 0,1,2,3,4,5,6,7); \
    acc[0][((Q)&1)*2] = __builtin_amdgcn_mfma_scale_f32_16x16x128_f8f6f4( \
        apan[0][(Q)>>1], bv0_, acc[0][((Q)&1)*2], 0,0, 0,0x7F7F7F7F, 0,0x7F7F7F7F); \
    acc[1][((Q)&1)*2] = __builtin_amdgcn_mfma_scale_f32_16x16x128_f8f6f4( \
        apan[1][(Q)>>1], bv0_, acc[1][((Q)&1)*2], 0,0, 0,0x7F7F7F7F, 0,0x7F7F7F7F); \
    i32x8 bv1_ = __builtin_shufflevector(BR[2], BR[3], 0,1,2,3,4,5,6,7); \
    acc[0][((Q)&1)*2+1] = __builtin_amdgcn_mfma_scale_f32_16x16x128_f8f6f4( \
        apan[0][(Q)>>1], bv1_, acc[0][((Q)&1)*2+1], 0,0, 0,0x7F7F7F7F, 0,0x7F7F7F7F); \
    acc[1][((Q)&1)*2+1] = __builtin_amdgcn_mfma_scale_f32_16x16x128_f8f6f4( \
        apan[1][(Q)>>1], bv1_, acc[1][((Q)&1)*2+1], 0,0, 0,0x7F7F7F7F, 0,0x7F7F7F7F); \
}

__global__ __launch_bounds__(256, 3) void big_gemm(
        const unsigned char* __restrict__ X,
        const unsigned char* __restrict__ WbT,
        const float* __restrict__ bw2,
        float* __restrict__ rowsum) {
    __shared__ unsigned char Bs[3][64 * 256];    // 3 x 16 KB
    __shared__ float biasL[1280];                // bw2*log2e for this col group
    const int t = threadIdx.x;
    const int wid = t >> 6, lane = t & 63;
    const int l15 = lane & 15, l4 = lane >> 4;
    const int g = blockIdx.x;                    // col group: 1280 cols
    const int row0 = blockIdx.y * 128 + wid * 32;
    const int NIT = 20;
    const float L2E = 1.44269504088896340736f;

    // ---- stage bias into LDS (only prologue VMEM besides DMA + A panel)
#pragma unroll
    for (int k = 0; k < 5; k++) {
        int idx = k * 256 + t;
        int col = g * 1280 + idx;
        biasL[idx] = (col < V_SZ) ? bw2[col] * L2E : -__builtin_inff();
    }

    // ---- hoisted swizzled LDS byte offsets: quarter q, read k = nn*2+gg
    int offs[16];
#pragma unroll
    for (int q = 0; q < 4; q++) {
        int kb = q >> 1, np = q & 1;
#pragma unroll
        for (int nn = 0; nn < 2; nn++)
#pragma unroll
            for (int gg = 0; gg < 2; gg++) {
                int ni = np * 2 + nn;
                int cc = ni * 16 + l15;
                int gr = kb * 8 + l4 * 2 + gg;
                offs[q * 4 + nn * 2 + gg] = cc * 256 + ((gr ^ (cc & 15)) << 4);
            }
    }

    auto dmaB = [&](int buf, int it) {
        const unsigned char* Bg = WbT + (size_t)(g * 1280 + it * 64) * 256;
#pragma unroll
        for (int q = 0; q < 4; q++) {
            int off = (wid * 4 + q) * 1024;      // wave-uniform dest (in tile)
            int F = off + lane * 16;             // this lane's dest byte
            int cc = F >> 8;                     // dest col within tile
            int s = (F >> 4) & 15;               // dest granule slot
            int srcg = s ^ (cc & 15);            // swizzled source granule
            __builtin_amdgcn_global_load_lds(
                (const __attribute__((address_space(1))) unsigned int*)(Bg + cc * 256 + (srcg << 4)),
                (__attribute__((address_space(3))) unsigned int*)(&Bs[buf][0] + off),
                16, 0, 0);
        }
    };

    dmaB(0, 0);
    // ---- A panel: 32 rows x K=256 in 32 VGPRs (linear, 32 B/lane/block)
    i32x8 apan[2][2];
    {
        const unsigned char* Ag = X + (size_t)row0 * 256;
#pragma unroll
        for (int mi = 0; mi < 2; mi++)
#pragma unroll
            for (int kb = 0; kb < 2; kb++)
                apan[mi][kb] = *(const i32x8*)(Ag + (mi * 16 + l15) * 256 + kb * 128 + l4 * 32);
    }
    dmaB(1, 1);
    __syncthreads();             // one-time full drain: tile0, tile1, A, bias

    i32x4 br0[4], br1[4];
    RDQ(&Bs[0][0], 0, br0);      // tile 0, quarter 0

    float PS[2][4] = {};

#pragma unroll 1
    for (int it = 0; it < NIT; it++) {
        if (it + 2 < NIT) dmaB((it + 2) % 3, it + 2);
        if (it < NIT - 2) {
            asm volatile("s_waitcnt vmcnt(4)" ::: "memory");
        } else {
            asm volatile("s_waitcnt vmcnt(0)" ::: "memory");
        }
        __builtin_amdgcn_s_barrier();
        const unsigned char* bufC = &Bs[it % 3][0];
        const unsigned char* bufN = &Bs[(it + 1) % 3][0];
        float bl[4];
#pragma unroll
        for (int ni = 0; ni < 4; ni++) bl[ni] = biasL[it * 64 + ni * 16 + l15];
        f32x4 acc[2][4] = {};
        RDQ(bufC, 1, br1); MFQ(0, br0);
        RDQ(bufC, 2, br0); MFQ(1, br1);
        RDQ(bufC, 3, br1); MFQ(2, br0);
        if (it + 1 < NIT) { RDQ(bufN, 0, br0); }
        MFQ(3, br1);
        // ---- epilogue: exp2(acc*log2e + biasL) into per-lane partials
#pragma unroll
        for (int ni = 0; ni < 4; ni++) {
            float bL = bl[ni];
#pragma unroll
            for (int mi = 0; mi < 2; mi++)
#pragma unroll
                for (int r = 0; r < 4; r++)
                    PS[mi][r] += exp2_hw(fmaf(acc[mi][ni][r], L2E, bL));
        }
    }
    // ---- one butterfly + atomics per wave ----
#pragma unroll
    for (int mi = 0; mi < 2; mi++)
#pragma unroll
        for (int r = 0; r < 4; r++) {
            float v = PS[mi][r];
            v += __shfl_xor(v, 1); v += __shfl_xor(v, 2);
            v += __shfl_xor(v, 4); v += __shfl_xor(v, 8);
            if (l15 == 0)
                atomicAdd(&rowsum[row0 + mi * 16 + l4 * 4 + r], v);
        }
}

// ---------------------------------------------------------------------------
// K4: build tables in LDS + CKY DP. 16 blocks (one per batch), 1024 thr,
// 16 lanes per (i) cell parallelize the split loop.
// ---------------------------------------------------------------------------
__global__ __launch_bounds__(1024) void dp_kernel(const float* __restrict__ tlog,
                          const float* __restrict__ glog,
                          const float* __restrict__ rowsum,
                          float* __restrict__ out) {
    __shared__ float Tl[1600], SHWl[1600], REl[1600];
    const int t = threadIdx.x;
    const int b = blockIdx.x;
    const float NEGINF = -__builtin_inff();
    for (int idx = t; idx < 1600; idx += 1024) {
        Tl[idx] = NEGINF; SHWl[idx] = NEGINF; REl[idx] = NEGINF;
    }
    __syncthreads();
    for (int p = t; p < NPAIR; p += 1024) {
        int i = 0, rem = p, len = L_SEQ - 1;
        while (rem >= len) { rem -= len; len--; i++; }
        int j = i + 1 + rem;
        int row = p * 16 + b;
        float tl = tlog[row];
        float re_v = (tl >= 0.f) ? -log1pf(__expf(-tl)) : (tl - log1pf(__expf(tl)));
        float sh_v = (tl <= 0.f) ? -log1pf(__expf(tl)) : (-tl - log1pf(__expf(-tl)));
        float wlp = glog[row] - __logf(rowsum[row]);
        SHWl[i * 40 + j] = sh_v + wlp;
        REl[i * 40 + j] = re_v;
    }
    if (t == 0) {
        int row = NPAIR * 16 + b;           // init cell
        Tl[0 * 40 + 1] = glog[row] - __logf(rowsum[row]);
    }
    if (t >= 1 && t <= 38) Tl[t * 40 + t + 1] = 0.f;
    __syncthreads();
    const int tg = t >> 4, li = t & 15;
    for (int gap = 2; gap <= L_SEQ - 1; gap++) {
        int n_i = L_SEQ - gap;
        float m = NEGINF, s = 0.f;
        int i = tg, j = tg + gap;
        if (tg < n_i) {
            for (int k = i + 1 + li; k < j; k += 16) {
                float v = Tl[i * 40 + k] + Tl[k * 40 + j]
                        + SHWl[i * 40 + k] + REl[k * 40 + j];
                if (v > m) { s = s * __expf(m - v) + 1.f; m = v; }
                else s += __expf(v - m);
            }
        }
#pragma unroll
        for (int off = 1; off < 16; off <<= 1) {
            float mo = __shfl_xor(m, off), so = __shfl_xor(s, off);
            float M = fmaxf(m, mo);
            float sn = 0.f;
            if (m > NEGINF) sn += s * __expf(m - M);
            if (mo > NEGINF) sn += so * __expf(mo - M);
            m = M; s = sn;
        }
        if (tg < n_i && li == 0) Tl[i * 40 + j] = m + __logf(s);
        __syncthreads();
    }
    if (t == 0) out[b] = Tl[39];
}

// ---------------------------------------------------------------------------
extern "C" void kernel_launch(void* const* d_in, const int* in_sizes, int n_in,
                              void* d_out, int out_size, void* d_ws, size_t ws_size,
                              hipStream_t stream) {
    const float* h        = (const float*)d_in[0];
    const int*   sentence = (const int*)d_in[1];
    const float* Wt1      = (const float*)d_in[2];
    const float* bt1      = (const float*)d_in[3];
    const float* Wt2      = (const float*)d_in[4];
    const float* bt2      = (const float*)d_in[5];
    const float* Ww1      = (const float*)d_in[6];
    const float* bw1      = (const float*)d_in[7];
    const float* Ww2      = (const float*)d_in[8];
    const float* bw2      = (const float*)d_in[9];
    float* out = (float*)d_out;

    char* ws = (char*)d_ws;
    size_t off = 0;
    float* UV = (float*)(ws + off);                    off += 4ull * 640 * 256 * 4;
    unsigned char* X = (unsigned char*)(ws + off);     off += (size_t)M_ROWS * 256;
    unsigned char* WbT = (unsigned char*)(ws + off);   off += (size_t)V_PAD * 256;
    float* WwT = (float*)(ws + off);                   off += (size_t)V_PAD * 256 * 4;
    float* rowsum = (float*)(ws + off);                off += (size_t)M_ROWS * 4;
    float* tlog = (float*)(ws + off);                  off += (size_t)M_ROWS * 4;
    float* glog = (float*)(ws + off);                  off += (size_t)M_ROWS * 4;

    const int zero_blocks = (M_ROWS + 255) / 256;      // 49
    prep_kernel<<<2880 + zero_blocks, 256, 0, stream>>>(
        Ww2, WwT, WbT, h, Wt1, Ww1, UV, rowsum);
    build_rows<<<M_ROWS / 4, 256, 0, stream>>>(UV, sentence, bt1, bw1, Wt2, bt2,
                                               WwT, bw2, X, tlog, glog);
    big_gemm<<<dim3(8, 98), 256, 0, stream>>>(X, WbT, bw2, rowsum);
    dp_kernel<<<16, 1024, 0, stream>>>(tlog, glog, rowsum, out);
}

// Round 8
// 206.345 us; speedup vs baseline: 1.9052x; 1.0138x over previous
//
#include <hip/hip_runtime.h>
#include <hip/hip_bf16.h>

#define L_SEQ 40
#define B_SZ  16
#define V_SZ  10000
#define V_PAD 10240
#define NPAIR 780
#define NROWP 784                 // 780 pairs + 1 init row + 3 pad "pairs"
#define M_ROWS (NROWP * B_SZ)     // 12544 rows = 49 strips of 256

typedef __attribute__((ext_vector_type(4))) float f32x4;
typedef __attribute__((ext_vector_type(4))) int   i32x4;
typedef __attribute__((ext_vector_type(8))) int   i32x8;

// ---------------------------------------------------------------------------
// float -> OCP e4m3fn. Prefer HW cvt; hand-rolled RNE fallback.
// ---------------------------------------------------------------------------
#if __has_builtin(__builtin_amdgcn_cvt_pk_fp8_f32)
__device__ __forceinline__ unsigned int pack4_fp8(float x0, float x1, float x2, float x3) {
    int lo = __builtin_amdgcn_cvt_pk_fp8_f32(x0, x1, 0, false);
    int full = __builtin_amdgcn_cvt_pk_fp8_f32(x2, x3, lo, true);
    return (unsigned int)full;
}
#else
__device__ __forceinline__ unsigned char f2e4m3(float f) {
    unsigned u = __float_as_uint(f);
    unsigned s = (u >> 24) & 0x80u;
    if ((u & 0x7FFFFFFFu) == 0) return (unsigned char)s;
    int E = (int)((u >> 23) & 0xFF) - 127 + 7;
    unsigned m = u & 0x7FFFFFu;
    if (E >= 16) return (unsigned char)(s | 0x7E);
    if (E >= 1) {
        unsigned keep = m >> 20, rest = m & 0xFFFFFu;
        keep += (rest > 0x80000u) || (rest == 0x80000u && (keep & 1));
        if (keep == 8) { keep = 0; E++; if (E >= 16) return (unsigned char)(s | 0x7E); }
        return (unsigned char)(s | (E << 3) | keep);
    }
    int shift = 1 - E;
    if (shift > 10) return (unsigned char)s;
    unsigned full = 0x800000u | m;
    unsigned sh = 20 + shift;
    unsigned keep = full >> sh, rem = full & ((1u << sh) - 1), half = 1u << (sh - 1);
    keep += (rem > half) || (rem == half && (keep & 1));
    if (keep >= 8) return (unsigned char)(s | (1 << 3));
    return (unsigned char)(s | keep);
}
__device__ __forceinline__ unsigned int pack4_fp8(float x0, float x1, float x2, float x3) {
    return (unsigned int)f2e4m3(x0) | ((unsigned int)f2e4m3(x1) << 8)
         | ((unsigned int)f2e4m3(x2) << 16) | ((unsigned int)f2e4m3(x3) << 24);
}
#endif

// 2^x via compiler-managed hardware exp (v_exp_f32 is base-2)
#if __has_builtin(__builtin_amdgcn_exp2f)
__device__ __forceinline__ float exp2_hw(float x) { return __builtin_amdgcn_exp2f(x); }
#else
__device__ __forceinline__ float exp2_hw(float x) { return __expf(x * 0.6931471805599453f); }
#endif

#if __has_builtin(__builtin_amdgcn_rcpf)
__device__ __forceinline__ float rcp_hw(float x) { return __builtin_amdgcn_rcpf(x); }
#else
__device__ __forceinline__ float rcp_hw(float x) { return 1.0f / x; }
#endif

// tanh(x) = 1 - 2/(e^{2x}+1): exp2 + add + rcp + fma = 5 VALU ops vs ~30 for
// ocml tanhf. Exact at +/-inf saturation; |err| ~1e-6 (rcp is ~1 ulp).
__device__ __forceinline__ float fast_tanh(float x) {
    float e = exp2_hw(x * 2.885390081777926814f);   // 2*log2(e)
    return fmaf(-2.0f, rcp_hw(e + 1.0f), 1.0f);
}

// Layout note: X and WbT are PLAIN row-major fp8 [row][k], 256 B per row.
// The MX-scaled MFMA (16x16x128) fragment is linear per lane: lane l holds
// row l&15, K-bytes (l>>4)*32 .. +31 — no byte permutation needed.

// ---------------------------------------------------------------------------
// K1: fused prep. [0,2560): transpose Ww2 -> WwT fp32 [10240,256] + WbT fp8
//     (linear row-major); [2560,2880): UV = h @ {Wt1,Ww1} halves; rest: zero
//     rowsum.
// ---------------------------------------------------------------------------
__global__ __launch_bounds__(256) void prep_kernel(
        const float* __restrict__ Ww2, float* __restrict__ WwT,
        unsigned char* __restrict__ WbT,
        const float* __restrict__ h, const float* __restrict__ Wt1,
        const float* __restrict__ Ww1, float* __restrict__ UV,
        float* __restrict__ rowsum) {
    const int bx = blockIdx.x;
    const int t = threadIdx.x;
    __shared__ float tile[32][33];
    __shared__ float hs[8 * 512];
    if (bx < 2560) {
        int v0 = (bx % 320) * 32;
        int K8 = bx / 320;           // k-tile index, k0 = K8*32
        int k0 = K8 * 32;
        int tx = t & 31, ty = t >> 5;   // 32 x 8
#pragma unroll
        for (int r = 0; r < 4; r++) {
            int k = k0 + ty + r * 8;
            int v = v0 + tx;
            tile[ty + r * 8][tx] = (v < V_SZ) ? Ww2[k * V_SZ + v] : 0.0f;   // tile[k][v]
        }
        __syncthreads();
        // fp32 transposed write
#pragma unroll
        for (int r = 0; r < 4; r++) {
            int vrow = ty + r * 8;
            WwT[(v0 + vrow) * 256 + (k0 + tx)] = tile[tx][vrow];
        }
        // fp8 write: thread -> (col v2, 4 consecutive k), linear layout
        int v2 = t >> 3;                 // 0..31
        int kq = 4 * (t & 7);            // local k base 0..28
        unsigned int pk = pack4_fp8(tile[kq][v2], tile[kq + 1][v2],
                                    tile[kq + 2][v2], tile[kq + 3][v2]);
        ((unsigned int*)WbT)[(v0 + v2) * 64 + K8 * 8 + (t & 7)] = pk;
    } else if (bx < 2880) {
        int ub = bx - 2560;
        int which = ub / 80;         // 0:Ut 1:Vt 2:Uw 3:Vw
        int m0 = (ub % 80) * 8;
        const float4* src = (const float4*)(h + (size_t)m0 * 512);
        float4* dst4 = (float4*)hs;
#pragma unroll
        for (int v = 0; v < 4; v++) dst4[v * 256 + t] = src[v * 256 + t];
        __syncthreads();
        const float* W = ((which < 2) ? Wt1 : Ww1) + ((which & 1) ? 512 * 256 : 0);
        float acc[8] = {};
        for (int f = 0; f < 512; f += 4) {
            float w0 = W[(f + 0) * 256 + t];
            float w1 = W[(f + 1) * 256 + t];
            float w2 = W[(f + 2) * 256 + t];
            float w3 = W[(f + 3) * 256 + t];
#pragma unroll
            for (int r = 0; r < 8; r++) {
                acc[r] += hs[r * 512 + f] * w0 + hs[r * 512 + f + 1] * w1
                        + hs[r * 512 + f + 2] * w2 + hs[r * 512 + f + 3] * w3;
            }
        }
        float* dst = UV + ((size_t)which * 640 + m0) * 256;
#pragma unroll
        for (int r = 0; r < 8; r++) dst[r * 256 + t] = acc[r];
    } else {
        int idx = (bx - 2880) * 256 + t;
        if (idx < M_ROWS) rowsum[idx] = 0.0f;
    }
}

// ---------------------------------------------------------------------------
// K2: per (pair,b) row: X = fp8(tanh(Uw[i]+Vw[j]+bw1)) linear row-major;
//     tlog/glog fp32 exact. One wave per row; p==780 is the init cell.
// ---------------------------------------------------------------------------
__global__ void build_rows(const float* __restrict__ UV,
                           const int* __restrict__ sentence,
                           const float* __restrict__ bt1,
                           const float* __restrict__ bw1,
                           const float* __restrict__ Wt2,
                           const float* __restrict__ bt2,
                           const float* __restrict__ WwT,
                           const float* __restrict__ bw2,
                           unsigned char* __restrict__ X,
                           float* __restrict__ tlog,
                           float* __restrict__ glog) {
    int w = blockIdx.x * 4 + (threadIdx.x >> 6);
    int lane = threadIdx.x & 63;
    int p = w >> 4, b = w & 15;
    int i = 0, j = 0;
    if (p < NPAIR) {
        int rem = p, len = L_SEQ - 1;
        while (rem >= len) { rem -= len; len--; i++; }
        j = i + 1 + rem;
    }
    int j1 = (j + 1 < L_SEQ) ? j + 1 : L_SEQ - 1;
    int tgt = sentence[j1 * B_SZ + b];
    const float4 ut = ((const float4*)(UV + 0 * 640 * 256 + (i * B_SZ + b) * 256))[lane];
    const float4 vt = ((const float4*)(UV + 1 * 640 * 256 + (j * B_SZ + b) * 256))[lane];
    const float4 uw = ((const float4*)(UV + 2 * 640 * 256 + (i * B_SZ + b) * 256))[lane];
    const float4 vw = ((const float4*)(UV + 3 * 640 * 256 + (j * B_SZ + b) * 256))[lane];
    const float4 bt = ((const float4*)bt1)[lane];
    const float4 bw = ((const float4*)bw1)[lane];
    const float4 w2 = ((const float4*)Wt2)[lane];
    const float4 wc = ((const float4*)(WwT + (size_t)tgt * 256))[lane];
    float xt0 = fast_tanh(ut.x + vt.x + bt.x), xt1 = fast_tanh(ut.y + vt.y + bt.y);
    float xt2 = fast_tanh(ut.z + vt.z + bt.z), xt3 = fast_tanh(ut.w + vt.w + bt.w);
    float xw0 = fast_tanh(uw.x + vw.x + bw.x), xw1 = fast_tanh(uw.y + vw.y + bw.y);
    float xw2 = fast_tanh(uw.z + vw.z + bw.z), xw3 = fast_tanh(uw.w + vw.w + bw.w);
    // linear: lane covers k = 4*lane .. 4*lane+3
    ((unsigned int*)X)[w * 64 + lane] = pack4_fp8(xw0, xw1, xw2, xw3);
    float td = xt0 * w2.x + xt1 * w2.y + xt2 * w2.z + xt3 * w2.w;
    float gd = xw0 * wc.x + xw1 * wc.y + xw2 * wc.z + xw3 * wc.w;
#pragma unroll
    for (int off = 32; off >= 1; off >>= 1) {
        td += __shfl_xor(td, off);
        gd += __shfl_xor(gd, off);
    }
    if (lane == 0) {
        tlog[w] = td + bt2[0];
        glog[w] = gd + bw2[tgt];
    }
}

// ---------------------------------------------------------------------------
// K3: MX-scaled fp8 GEMM (16x16x128, unit scales) + fused sum-exp.
// Round-8 restructure (lesson: 4-wave blocks = 1 wave/SIMD = zero
// MFMA/epilogue overlap; 784 blocks = 3 ragged rounds):
//  * Block = 256 rows x 2048 cols, 8 waves -> 2 waves/SIMD from the SAME
//    block: wave A's exp2 epilogue overlaps wave B's MFMAs.
//  * Grid (5 col-groups, 49 strips) = 245 blocks <= 256 CUs: every block
//    resident, single round, no tail.
//  * Race-fixed schedule (old dmaB-before-barrier raced a slow wave's
//    buffer reads vs a fast wave's DMA issue):
//      vmcnt(0)   <- drains tile it+1, issued a FULL iteration ago (~free)
//      s_barrier  <- all reads of buffer (it+2)%3 from iter it-1 done
//      dmaB it+2  <- WAR-safe; in flight across the whole compute phase
//      quarter-pipelined ds_read/MFMA (+setprio around MFMAs: waves are
//      now role-split so priority has something to arbitrate)
//  * No VMEM in loop except DMA (bias in LDS, round-7 fix).
// LDS = 3 x 16 KB + 8 KB bias = 56 KB. ~150 VGPR/wave, 2 waves/SIMD.
// ---------------------------------------------------------------------------
#define RDQ(BASE, Q, BR) \
    BR[0] = *(const i32x4*)((BASE) + offs[(Q)*4+0]); \
    BR[1] = *(const i32x4*)((BASE) + offs[(Q)*4+1]); \
    BR[2] = *(const i32x4*)((BASE) + offs[(Q)*4+2]); \
    BR[3] = *(const i32x4*)((BASE) + offs[(Q)*4+3]);

#define MFQ(Q, BR) { \
    i32x8 bv0_ = __builtin_shufflevector(BR[0], BR[1], 0,1,2,3,4,5,6,7); \
    acc[0][((Q)&1)*2] = __builtin_amdgcn_mfma_scale_f32_16x16x128_f8f6f4( \
        apan[0][(Q)>>1], bv0_, acc[0][((Q)&1)*2], 0,0, 0,0x7F7F7F7F, 0,0x7F7F7F7F); \
    acc[1][((Q)&1)*2] = __builtin_amdgcn_mfma_scale_f32_16x16x128_f8f6f4( \
        apan[1][(Q)>>1], bv0_, acc[1][((Q)&1)*2], 0,0, 0,0x7F7F7F7F, 0,0x7F7F7F7F); \
    i32x8 bv1_ = __builtin_shufflevector(BR[2], BR[3], 0,1,2,3,4,5,6,7); \
    acc[0][((Q)&1)*2+1] = __builtin_amdgcn_mfma_scale_f32_16x16x128_f8f6f4( \
        apan[0][(Q)>>1], bv1_, acc[0][((Q)&1)*2+1], 0,0, 0,0x7F7F7F7F, 0,0x7F7F7F7F); \
    acc[1][((Q)&1)*2+1] = __builtin_amdgcn_mfma_scale_f32_16x16x128_f8f6f4( \
        apan[1][(Q)>>1], bv1_, acc[1][((Q)&1)*2+1], 0,0, 0,0x7F7F7F7F, 0,0x7F7F7F7F); \
}

__global__ __launch_bounds__(512, 2) void big_gemm(
        const unsigned char* __restrict__ X,
        const unsigned char* __restrict__ WbT,
        const float* __restrict__ bw2,
        float* __restrict__ rowsum) {
    __shared__ unsigned char Bs[3][64 * 256];    // 3 x 16 KB
    __shared__ float biasL[2048];                // bw2*log2e for this col group
    const int t = threadIdx.x;
    const int wid = t >> 6, lane = t & 63;
    const int l15 = lane & 15, l4 = lane >> 4;
    const int g = blockIdx.x;                    // col group: 2048 cols
    const int row0 = blockIdx.y * 256 + wid * 32;
    const int NIT = 32;
    const float L2E = 1.44269504088896340736f;

    // ---- stage bias into LDS (prologue VMEM only)
#pragma unroll
    for (int k = 0; k < 4; k++) {
        int idx = k * 512 + t;
        int col = g * 2048 + idx;
        biasL[idx] = (col < V_SZ) ? bw2[col] * L2E : -__builtin_inff();
    }

    // ---- hoisted swizzled LDS byte offsets: quarter q, read k = nn*2+gg
    int offs[16];
#pragma unroll
    for (int q = 0; q < 4; q++) {
        int kb = q >> 1, np = q & 1;
#pragma unroll
        for (int nn = 0; nn < 2; nn++)
#pragma unroll
            for (int gg = 0; gg < 2; gg++) {
                int ni = np * 2 + nn;
                int cc = ni * 16 + l15;
                int gr = kb * 8 + l4 * 2 + gg;
                offs[q * 4 + nn * 2 + gg] = cc * 256 + ((gr ^ (cc & 15)) << 4);
            }
    }

    // 8 waves x 2 loads x 64 lanes x 16 B = 16 KB tile
    auto dmaB = [&](int buf, int it) {
        const unsigned char* Bg = WbT + (size_t)(g * 2048 + it * 64) * 256;
#pragma unroll
        for (int q = 0; q < 2; q++) {
            int off = (wid * 2 + q) * 1024;      // wave-uniform dest (in tile)
            int F = off + lane * 16;             // this lane's dest byte
            int cc = F >> 8;                     // dest col within tile
            int s = (F >> 4) & 15;               // dest granule slot
            int srcg = s ^ (cc & 15);            // swizzled source granule
            __builtin_amdgcn_global_load_lds(
                (const __attribute__((address_space(1))) unsigned int*)(Bg + cc * 256 + (srcg << 4)),
                (__attribute__((address_space(3))) unsigned int*)(&Bs[buf][0] + off),
                16, 0, 0);
        }
    };

    dmaB(0, 0);
    // ---- A panel: 32 rows x K=256 in 32 VGPRs (linear, 32 B/lane/block)
    i32x8 apan[2][2];
    {
        const unsigned char* Ag = X + (size_t)row0 * 256;
#pragma unroll
        for (int mi = 0; mi < 2; mi++)
#pragma unroll
            for (int kb = 0; kb < 2; kb++)
                apan[mi][kb] = *(const i32x8*)(Ag + (mi * 16 + l15) * 256 + kb * 128 + l4 * 32);
    }
    dmaB(1, 1);
    __syncthreads();             // one-time full drain: tile0, tile1, A, bias

    i32x4 br0[4], br1[4];
    RDQ(&Bs[0][0], 0, br0);      // tile 0, quarter 0

    float PS[2][4] = {};
    int bc = 0, bp = 2;          // current / dma-target buffer indices

#pragma unroll 1
    for (int it = 0; it < NIT; it++) {
        // tile it+1 (issued one full iteration ago) retires ~free; barrier
        // THEN dma keeps the buffer-reuse WAR ordered (race fix).
        asm volatile("s_waitcnt vmcnt(0)" ::: "memory");
        __builtin_amdgcn_s_barrier();
        if (it + 2 < NIT) dmaB(bp, it + 2);
        const unsigned char* bufC = &Bs[bc][0];
        int bn = (bc == 2) ? 0 : bc + 1;
        const unsigned char* bufN = &Bs[bn][0];
        float bl[4];
#pragma unroll
        for (int ni = 0; ni < 4; ni++) bl[ni] = biasL[it * 64 + ni * 16 + l15];
        f32x4 acc[2][4] = {};
        __builtin_amdgcn_s_setprio(1);
        RDQ(bufC, 1, br1); MFQ(0, br0);
        RDQ(bufC, 2, br0); MFQ(1, br1);
        RDQ(bufC, 3, br1); MFQ(2, br0);
        if (it + 1 < NIT) { RDQ(bufN, 0, br0); }
        MFQ(3, br1);
        __builtin_amdgcn_s_setprio(0);
        // ---- epilogue: exp2(acc*log2e + biasL) into per-lane partials
#pragma unroll
        for (int ni = 0; ni < 4; ni++) {
            float bL = bl[ni];
#pragma unroll
            for (int mi = 0; mi < 2; mi++)
#pragma unroll
                for (int r = 0; r < 4; r++)
                    PS[mi][r] += exp2_hw(fmaf(acc[mi][ni][r], L2E, bL));
        }
        bc = bn;
        bp = (bp == 2) ? 0 : bp + 1;
    }
    // ---- one butterfly + atomics per wave ----
#pragma unroll
    for (int mi = 0; mi < 2; mi++)
#pragma unroll
        for (int r = 0; r < 4; r++) {
            float v = PS[mi][r];
            v += __shfl_xor(v, 1); v += __shfl_xor(v, 2);
            v += __shfl_xor(v, 4); v += __shfl_xor(v, 8);
            if (l15 == 0)
                atomicAdd(&rowsum[row0 + mi * 16 + l4 * 4 + r], v);
        }
}

// ---------------------------------------------------------------------------
// K4: build tables in LDS + CKY DP. 16 blocks (one per batch), 1024 thr,
// 16 lanes per (i) cell parallelize the split loop.
// ---------------------------------------------------------------------------
__global__ __launch_bounds__(1024) void dp_kernel(const float* __restrict__ tlog,
                          const float* __restrict__ glog,
                          const float* __restrict__ rowsum,
                          float* __restrict__ out) {
    __shared__ float Tl[1600], SHWl[1600], REl[1600];
    const int t = threadIdx.x;
    const int b = blockIdx.x;
    const float NEGINF = -__builtin_inff();
    for (int idx = t; idx < 1600; idx += 1024) {
        Tl[idx] = NEGINF; SHWl[idx] = NEGINF; REl[idx] = NEGINF;
    }
    __syncthreads();
    for (int p = t; p < NPAIR; p += 1024) {
        int i = 0, rem = p, len = L_SEQ - 1;
        while (rem >= len) { rem -= len; len--; i++; }
        int j = i + 1 + rem;
        int row = p * 16 + b;
        float tl = tlog[row];
        float re_v = (tl >= 0.f) ? -log1pf(__expf(-tl)) : (tl - log1pf(__expf(tl)));
        float sh_v = (tl <= 0.f) ? -log1pf(__expf(tl)) : (-tl - log1pf(__expf(-tl)));
        float wlp = glog[row] - __logf(rowsum[row]);
        SHWl[i * 40 + j] = sh_v + wlp;
        REl[i * 40 + j] = re_v;
    }
    if (t == 0) {
        int row = NPAIR * 16 + b;           // init cell
        Tl[0 * 40 + 1] = glog[row] - __logf(rowsum[row]);
    }
    if (t >= 1 && t <= 38) Tl[t * 40 + t + 1] = 0.f;
    __syncthreads();
    const int tg = t >> 4, li = t & 15;
    for (int gap = 2; gap <= L_SEQ - 1; gap++) {
        int n_i = L_SEQ - gap;
        float m = NEGINF, s = 0.f;
        int i = tg, j = tg + gap;
        if (tg < n_i) {
            for (int k = i + 1 + li; k < j; k += 16) {
                float v = Tl[i * 40 + k] + Tl[k * 40 + j]
                        + SHWl[i * 40 + k] + REl[k * 40 + j];
                if (v > m) { s = s * __expf(m - v) + 1.f; m = v; }
                else s += __expf(v - m);
            }
        }
#pragma unroll
        for (int off = 1; off < 16; off <<= 1) {
            float mo = __shfl_xor(m, off), so = __shfl_xor(s, off);
            float M = fmaxf(m, mo);
            float sn = 0.f;
            if (m > NEGINF) sn += s * __expf(m - M);
            if (mo > NEGINF) sn += so * __expf(mo - M);
            m = M; s = sn;
        }
        if (tg < n_i && li == 0) Tl[i * 40 + j] = m + __logf(s);
        __syncthreads();
    }
    if (t == 0) out[b] = Tl[39];
}

// ---------------------------------------------------------------------------
extern "C" void kernel_launch(void* const* d_in, const int* in_sizes, int n_in,
                              void* d_out, int out_size, void* d_ws, size_t ws_size,
                              hipStream_t stream) {
    const float* h        = (const float*)d_in[0];
    const int*   sentence = (const int*)d_in[1];
    const float* Wt1      = (const float*)d_in[2];
    const float* bt1      = (const float*)d_in[3];
    const float* Wt2      = (const float*)d_in[4];
    const float* bt2      = (const float*)d_in[5];
    const float* Ww1      = (const float*)d_in[6];
    const float* bw1      = (const float*)d_in[7];
    const float* Ww2      = (const float*)d_in[8];
    const float* bw2      = (const float*)d_in[9];
    float* out = (float*)d_out;

    char* ws = (char*)d_ws;
    size_t off = 0;
    float* UV = (float*)(ws + off);                    off += 4ull * 640 * 256 * 4;
    unsigned char* X = (unsigned char*)(ws + off);     off += (size_t)M_ROWS * 256;
    unsigned char* WbT = (unsigned char*)(ws + off);   off += (size_t)V_PAD * 256;
    float* WwT = (float*)(ws + off);                   off += (size_t)V_PAD * 256 * 4;
    float* rowsum = (float*)(ws + off);                off += (size_t)M_ROWS * 4;
    float* tlog = (float*)(ws + off);                  off += (size_t)M_ROWS * 4;
    float* glog = (float*)(ws + off);                  off += (size_t)M_ROWS * 4;

    const int zero_blocks = (M_ROWS + 255) / 256;      // 49
    prep_kernel<<<2880 + zero_blocks, 256, 0, stream>>>(
        Ww2, WwT, WbT, h, Wt1, Ww1, UV, rowsum);
    build_rows<<<M_ROWS / 4, 256, 0, stream>>>(UV, sentence, bt1, bw1, Wt2, bt2,
                                               WwT, bw2, X, tlog, glog);
    big_gemm<<<dim3(5, 49), 512, 0, stream>>>(X, WbT, bw2, rowsum);
    dp_kernel<<<16, 1024, 0, stream>>>(tlog, glog, rowsum, out);
}

// Round 11
// 198.929 us; speedup vs baseline: 1.9763x; 1.0373x over previous
//
#include <hip/hip_runtime.h>
#include <hip/hip_bf16.h>

#define L_SEQ 40
#define B_SZ  16
#define V_SZ  10000
#define V_PAD 10240
#define NPAIR 780
#define NROWP 784                 // 780 pairs + 1 init row + 3 pad "pairs"
#define M_ROWS (NROWP * B_SZ)     // 12544 rows = 49 strips of 256

typedef __attribute__((ext_vector_type(4))) float f32x4;
typedef __attribute__((ext_vector_type(4))) int   i32x4;
typedef __attribute__((ext_vector_type(8))) int   i32x8;

// ---------------------------------------------------------------------------
// float -> OCP e4m3fn. Prefer HW cvt; hand-rolled RNE fallback.
// ---------------------------------------------------------------------------
#if __has_builtin(__builtin_amdgcn_cvt_pk_fp8_f32)
__device__ __forceinline__ unsigned int pack4_fp8(float x0, float x1, float x2, float x3) {
    int lo = __builtin_amdgcn_cvt_pk_fp8_f32(x0, x1, 0, false);
    int full = __builtin_amdgcn_cvt_pk_fp8_f32(x2, x3, lo, true);
    return (unsigned int)full;
}
#else
__device__ __forceinline__ unsigned char f2e4m3(float f) {
    unsigned u = __float_as_uint(f);
    unsigned s = (u >> 24) & 0x80u;
    if ((u & 0x7FFFFFFFu) == 0) return (unsigned char)s;
    int E = (int)((u >> 23) & 0xFF) - 127 + 7;
    unsigned m = u & 0x7FFFFFu;
    if (E >= 16) return (unsigned char)(s | 0x7E);
    if (E >= 1) {
        unsigned keep = m >> 20, rest = m & 0xFFFFFu;
        keep += (rest > 0x80000u) || (rest == 0x80000u && (keep & 1));
        if (keep == 8) { keep = 0; E++; if (E >= 16) return (unsigned char)(s | 0x7E); }
        return (unsigned char)(s | (E << 3) | keep);
    }
    int shift = 1 - E;
    if (shift > 10) return (unsigned char)s;
    unsigned full = 0x800000u | m;
    unsigned sh = 20 + shift;
    unsigned keep = full >> sh, rem = full & ((1u << sh) - 1), half = 1u << (sh - 1);
    keep += (rem > half) || (rem == half && (keep & 1));
    if (keep >= 8) return (unsigned char)(s | (1 << 3));
    return (unsigned char)(s | keep);
}
__device__ __forceinline__ unsigned int pack4_fp8(float x0, float x1, float x2, float x3) {
    return (unsigned int)f2e4m3(x0) | ((unsigned int)f2e4m3(x1) << 8)
         | ((unsigned int)f2e4m3(x2) << 16) | ((unsigned int)f2e4m3(x3) << 24);
}
#endif

// 2^x via compiler-managed hardware exp (v_exp_f32 is base-2)
#if __has_builtin(__builtin_amdgcn_exp2f)
__device__ __forceinline__ float exp2_hw(float x) { return __builtin_amdgcn_exp2f(x); }
#else
__device__ __forceinline__ float exp2_hw(float x) { return __expf(x * 0.6931471805599453f); }
#endif

#if __has_builtin(__builtin_amdgcn_rcpf)
__device__ __forceinline__ float rcp_hw(float x) { return __builtin_amdgcn_rcpf(x); }
#else
__device__ __forceinline__ float rcp_hw(float x) { return 1.0f / x; }
#endif

// tanh(x) = 1 - 2/(e^{2x}+1): exp2 + add + rcp + fma = 5 VALU ops vs ~30 for
// ocml tanhf. Exact at +/-inf saturation; |err| ~1e-6 (rcp is ~1 ulp).
__device__ __forceinline__ float fast_tanh(float x) {
    float e = exp2_hw(x * 2.885390081777926814f);   // 2*log2(e)
    return fmaf(-2.0f, rcp_hw(e + 1.0f), 1.0f);
}

// Layout note: X and WbT are PLAIN row-major fp8 [row][k], 256 B per row.
// The MX-scaled MFMA (16x16x128) fragment is linear per lane: lane l holds
// row l&15, K-bytes (l>>4)*32 .. +31 — no byte permutation needed.

// ---------------------------------------------------------------------------
// K1: fused prep, round-9 re-tile (old version: 2560 tiny 4 KB transpose
// blocks = 10 latency-bound dispatch rounds at 570 GB/s, 9% of BW).
//  * Transpose: 640 blocks, tile = 32 k x 128 v, float4 loads (16 B/lane),
//    one LDS column read feeds BOTH the fp32 float4 WwT store and the fp8
//    pack. 2.5 rounds instead of 10.
//  * UV: f unrolled by 4 with ds_read_b128 broadcast reads (44 vs 68
//    instrs per f-step).
//  * rowsum zeroing moved to hipMemsetAsync.
//  * LDS: transpose tile and UV hs share one union buffer (16.9 KB) ->
//    ~8 blocks/CU for latency hiding.
// ---------------------------------------------------------------------------
__global__ __launch_bounds__(256) void prep_kernel(
        const float* __restrict__ Ww2, float* __restrict__ WwT,
        unsigned char* __restrict__ WbT,
        const float* __restrict__ h, const float* __restrict__ Wt1,
        const float* __restrict__ Ww1, float* __restrict__ UV) {
    const int bx = blockIdx.x;
    const int t = threadIdx.x;
    __shared__ float smem[32 * 132];             // union: tile[32][132] / hs[8*512]
    if (bx < 640) {
        // ---- transpose block: 32 k x 128 v
        float (*tile)[132] = (float (*)[132])smem;
        int v0 = (bx % 80) * 128;
        int k0 = (bx / 80) * 32;
        int tx4 = t & 31, ky = t >> 5;           // float4 col, 8 rows/pass
        int v = v0 + tx4 * 4;
#pragma unroll
        for (int r = 0; r < 4; r++) {
            int k = k0 + ky + r * 8;
            float4 val = make_float4(0.f, 0.f, 0.f, 0.f);
            if (v < V_SZ) val = *(const float4*)(Ww2 + (size_t)k * V_SZ + v);
            *(float4*)(&tile[ky + r * 8][tx4 * 4]) = val;
        }
        __syncthreads();
        int kx4 = t & 7, vr8 = t >> 3;           // 8 float4 per 32 k, 32 v/pass
#pragma unroll
        for (int pass = 0; pass < 4; pass++) {
            int vr = vr8 + pass * 32;
            float c0 = tile[kx4 * 4 + 0][vr];
            float c1 = tile[kx4 * 4 + 1][vr];
            float c2 = tile[kx4 * 4 + 2][vr];
            float c3 = tile[kx4 * 4 + 3][vr];
            float4 cv = make_float4(c0, c1, c2, c3);
            *(float4*)(WwT + (size_t)(v0 + vr) * 256 + k0 + kx4 * 4) = cv;
            ((unsigned int*)WbT)[(size_t)(v0 + vr) * 64 + (k0 >> 2) + kx4] =
                pack4_fp8(c0, c1, c2, c3);
        }
    } else {
        // ---- UV block: 8 h-rows x 256 cols of one weight half
        float* hs = smem;                        // 8*512 floats = 16 KB
        int ub = bx - 640;
        int which = ub / 80;         // 0:Ut 1:Vt 2:Uw 3:Vw
        int m0 = (ub % 80) * 8;
        const float4* src = (const float4*)(h + (size_t)m0 * 512);
        float4* dst4 = (float4*)hs;
#pragma unroll
        for (int v = 0; v < 4; v++) dst4[v * 256 + t] = src[v * 256 + t];
        __syncthreads();
        const float* W = ((which < 2) ? Wt1 : Ww1) + ((which & 1) ? 512 * 256 : 0);
        float acc[8] = {};
        for (int f = 0; f < 512; f += 4) {
            float w0 = W[(f + 0) * 256 + t];
            float w1 = W[(f + 1) * 256 + t];
            float w2 = W[(f + 2) * 256 + t];
            float w3 = W[(f + 3) * 256 + t];
#pragma unroll
            for (int r = 0; r < 8; r++) {
                float4 hv = *(const float4*)(hs + r * 512 + f);
                acc[r] += hv.x * w0 + hv.y * w1 + hv.z * w2 + hv.w * w3;
            }
        }
        float* dst = UV + ((size_t)which * 640 + m0) * 256;
#pragma unroll
        for (int r = 0; r < 8; r++) dst[r * 256 + t] = acc[r];
    }
}

// ---------------------------------------------------------------------------
// K2: per (pair,b) row: X = fp8(tanh(Uw[i]+Vw[j]+bw1)) linear row-major;
//     tlog/glog fp32 exact. One wave per row; p==780 is the init cell.
// ---------------------------------------------------------------------------
__global__ void build_rows(const float* __restrict__ UV,
                           const int* __restrict__ sentence,
                           const float* __restrict__ bt1,
                           const float* __restrict__ bw1,
                           const float* __restrict__ Wt2,
                           const float* __restrict__ bt2,
                           const float* __restrict__ WwT,
                           const float* __restrict__ bw2,
                           unsigned char* __restrict__ X,
                           float* __restrict__ tlog,
                           float* __restrict__ glog) {
    int w = blockIdx.x * 4 + (threadIdx.x >> 6);
    int lane = threadIdx.x & 63;
    int p = w >> 4, b = w & 15;
    int i = 0, j = 0;
    if (p < NPAIR) {
        int rem = p, len = L_SEQ - 1;
        while (rem >= len) { rem -= len; len--; i++; }
        j = i + 1 + rem;
    }
    int j1 = (j + 1 < L_SEQ) ? j + 1 : L_SEQ - 1;
    int tgt = sentence[j1 * B_SZ + b];
    const float4 ut = ((const float4*)(UV + 0 * 640 * 256 + (i * B_SZ + b) * 256))[lane];
    const float4 vt = ((const float4*)(UV + 1 * 640 * 256 + (j * B_SZ + b) * 256))[lane];
    const float4 uw = ((const float4*)(UV + 2 * 640 * 256 + (i * B_SZ + b) * 256))[lane];
    const float4 vw = ((const float4*)(UV + 3 * 640 * 256 + (j * B_SZ + b) * 256))[lane];
    const float4 bt = ((const float4*)bt1)[lane];
    const float4 bw = ((const float4*)bw1)[lane];
    const float4 w2 = ((const float4*)Wt2)[lane];
    const float4 wc = ((const float4*)(WwT + (size_t)tgt * 256))[lane];
    float xt0 = fast_tanh(ut.x + vt.x + bt.x), xt1 = fast_tanh(ut.y + vt.y + bt.y);
    float xt2 = fast_tanh(ut.z + vt.z + bt.z), xt3 = fast_tanh(ut.w + vt.w + bt.w);
    float xw0 = fast_tanh(uw.x + vw.x + bw.x), xw1 = fast_tanh(uw.y + vw.y + bw.y);
    float xw2 = fast_tanh(uw.z + vw.z + bw.z), xw3 = fast_tanh(uw.w + vw.w + bw.w);
    // linear: lane covers k = 4*lane .. 4*lane+3
    ((unsigned int*)X)[w * 64 + lane] = pack4_fp8(xw0, xw1, xw2, xw3);
    float td = xt0 * w2.x + xt1 * w2.y + xt2 * w2.z + xt3 * w2.w;
    float gd = xw0 * wc.x + xw1 * wc.y + xw2 * wc.z + xw3 * wc.w;
#pragma unroll
    for (int off = 32; off >= 1; off >>= 1) {
        td += __shfl_xor(td, off);
        gd += __shfl_xor(gd, off);
    }
    if (lane == 0) {
        tlog[w] = td + bt2[0];
        glog[w] = gd + bw2[tgt];
    }
}

// ---------------------------------------------------------------------------
// K3: MX-scaled fp8 GEMM (16x16x128, unit scales) + fused sum-exp.
// 8 waves/block (2/SIMD: MFMA phase of one wave overlaps exp2 epilogue of
// the other), 245 blocks = single resident round. Race-fixed counted-DMA
// schedule; no VMEM in loop except DMA; bias in LDS. (Round-8 structure,
// unchanged.)
// ---------------------------------------------------------------------------
#define RDQ(BASE, Q, BR) \
    BR[0] = *(const i32x4*)((BASE) + offs[(Q)*4+0]); \
    BR[1] = *(const i32x4*)((BASE) + offs[(Q)*4+1]); \
    BR[2] = *(const i32x4*)((BASE) + offs[(Q)*4+2]); \
    BR[3] = *(const i32x4*)((BASE) + offs[(Q)*4+3]);

#define MFQ(Q, BR) { \
    i32x8 bv0_ = __builtin_shufflevector(BR[0], BR[1], 0,1,2,3,4,5,6,7); \
    acc[0][((Q)&1)*2] = __builtin_amdgcn_mfma_scale_f32_16x16x128_f8f6f4( \
        apan[0][(Q)>>1], bv0_, acc[0][((Q)&1)*2], 0,0, 0,0x7F7F7F7F, 0,0x7F7F7F7F); \
    acc[1][((Q)&1)*2] = __builtin_amdgcn_mfma_scale_f32_16x16x128_f8f6f4( \
        apan[1][(Q)>>1], bv0_, acc[1][((Q)&1)*2], 0,0, 0,0x7F7F7F7F, 0,0x7F7F7F7F); \
    i32x8 bv1_ = __builtin_shufflevector(BR[2], BR[3], 0,1,2,3,4,5,6,7); \
    acc[0][((Q)&1)*2+1] = __builtin_amdgcn_mfma_scale_f32_16x16x128_f8f6f4( \
        apan[0][(Q)>>1], bv1_, acc[0][((Q)&1)*2+1], 0,0, 0,0x7F7F7F7F, 0,0x7F7F7F7F); \
    acc[1][((Q)&1)*2+1] = __builtin_amdgcn_mfma_scale_f32_16x16x128_f8f6f4( \
        apan[1][(Q)>>1], bv1_, acc[1][((Q)&1)*2+1], 0,0, 0,0x7F7F7F7F, 0,0x7F7F7F7F); \
}

__global__ __launch_bounds__(512, 2) void big_gemm(
        const unsigned char* __restrict__ X,
        const unsigned char* __restrict__ WbT,
        const float* __restrict__ bw2,
        float* __restrict__ rowsum) {
    __shared__ unsigned char Bs[3][64 * 256];    // 3 x 16 KB
    __shared__ float biasL[2048];                // bw2*log2e for this col group
    const int t = threadIdx.x;
    const int wid = t >> 6, lane = t & 63;
    const int l15 = lane & 15, l4 = lane >> 4;
    const int g = blockIdx.x;                    // col group: 2048 cols
    const int row0 = blockIdx.y * 256 + wid * 32;
    const int NIT = 32;
    const float L2E = 1.44269504088896340736f;

    // ---- stage bias into LDS (prologue VMEM only)
#pragma unroll
    for (int k = 0; k < 4; k++) {
        int idx = k * 512 + t;
        int col = g * 2048 + idx;
        biasL[idx] = (col < V_SZ) ? bw2[col] * L2E : -__builtin_inff();
    }

    // ---- hoisted swizzled LDS byte offsets: quarter q, read k = nn*2+gg
    int offs[16];
#pragma unroll
    for (int q = 0; q < 4; q++) {
        int kb = q >> 1, np = q & 1;
#pragma unroll
        for (int nn = 0; nn < 2; nn++)
#pragma unroll
            for (int gg = 0; gg < 2; gg++) {
                int ni = np * 2 + nn;
                int cc = ni * 16 + l15;
                int gr = kb * 8 + l4 * 2 + gg;
                offs[q * 4 + nn * 2 + gg] = cc * 256 + ((gr ^ (cc & 15)) << 4);
            }
    }

    // 8 waves x 2 loads x 64 lanes x 16 B = 16 KB tile
    auto dmaB = [&](int buf, int it) {
        const unsigned char* Bg = WbT + (size_t)(g * 2048 + it * 64) * 256;
#pragma unroll
        for (int q = 0; q < 2; q++) {
            int off = (wid * 2 + q) * 1024;      // wave-uniform dest (in tile)
            int F = off + lane * 16;             // this lane's dest byte
            int cc = F >> 8;                     // dest col within tile
            int s = (F >> 4) & 15;               // dest granule slot
            int srcg = s ^ (cc & 15);            // swizzled source granule
            __builtin_amdgcn_global_load_lds(
                (const __attribute__((address_space(1))) unsigned int*)(Bg + cc * 256 + (srcg << 4)),
                (__attribute__((address_space(3))) unsigned int*)(&Bs[buf][0] + off),
                16, 0, 0);
        }
    };

    dmaB(0, 0);
    // ---- A panel: 32 rows x K=256 in 32 VGPRs (linear, 32 B/lane/block)
    i32x8 apan[2][2];
    {
        const unsigned char* Ag = X + (size_t)row0 * 256;
#pragma unroll
        for (int mi = 0; mi < 2; mi++)
#pragma unroll
            for (int kb = 0; kb < 2; kb++)
                apan[mi][kb] = *(const i32x8*)(Ag + (mi * 16 + l15) * 256 + kb * 128 + l4 * 32);
    }
    dmaB(1, 1);
    __syncthreads();             // one-time full drain: tile0, tile1, A, bias

    i32x4 br0[4], br1[4];
    RDQ(&Bs[0][0], 0, br0);      // tile 0, quarter 0

    float PS[2][4] = {};
    int bc = 0, bp = 2;          // current / dma-target buffer indices

#pragma unroll 1
    for (int it = 0; it < NIT; it++) {
        // tile it+1 (issued one full iteration ago) retires ~free; barrier
        // THEN dma keeps the buffer-reuse WAR ordered (race fix).
        asm volatile("s_waitcnt vmcnt(0)" ::: "memory");
        __builtin_amdgcn_s_barrier();
        if (it + 2 < NIT) dmaB(bp, it + 2);
        const unsigned char* bufC = &Bs[bc][0];
        int bn = (bc == 2) ? 0 : bc + 1;
        const unsigned char* bufN = &Bs[bn][0];
        float bl[4];
#pragma unroll
        for (int ni = 0; ni < 4; ni++) bl[ni] = biasL[it * 64 + ni * 16 + l15];
        f32x4 acc[2][4] = {};
        __builtin_amdgcn_s_setprio(1);
        RDQ(bufC, 1, br1); MFQ(0, br0);
        RDQ(bufC, 2, br0); MFQ(1, br1);
        RDQ(bufC, 3, br1); MFQ(2, br0);
        if (it + 1 < NIT) { RDQ(bufN, 0, br0); }
        MFQ(3, br1);
        __builtin_amdgcn_s_setprio(0);
        // ---- epilogue: exp2(acc*log2e + biasL) into per-lane partials
#pragma unroll
        for (int ni = 0; ni < 4; ni++) {
            float bL = bl[ni];
#pragma unroll
            for (int mi = 0; mi < 2; mi++)
#pragma unroll
                for (int r = 0; r < 4; r++)
                    PS[mi][r] += exp2_hw(fmaf(acc[mi][ni][r], L2E, bL));
        }
        bc = bn;
        bp = (bp == 2) ? 0 : bp + 1;
    }
    // ---- one butterfly + atomics per wave ----
#pragma unroll
    for (int mi = 0; mi < 2; mi++)
#pragma unroll
        for (int r = 0; r < 4; r++) {
            float v = PS[mi][r];
            v += __shfl_xor(v, 1); v += __shfl_xor(v, 2);
            v += __shfl_xor(v, 4); v += __shfl_xor(v, 8);
            if (l15 == 0)
                atomicAdd(&rowsum[row0 + mi * 16 + l4 * 4 + r], v);
        }
}

// ---------------------------------------------------------------------------
// K4: build tables in LDS + CKY DP. 16 blocks (one per batch), 1024 thr,
// 16 lanes per (i) cell parallelize the split loop.
// ---------------------------------------------------------------------------
__global__ __launch_bounds__(1024) void dp_kernel(const float* __restrict__ tlog,
                          const float* __restrict__ glog,
                          const float* __restrict__ rowsum,
                          float* __restrict__ out) {
    __shared__ float Tl[1600], SHWl[1600], REl[1600];
    const int t = threadIdx.x;
    const int b = blockIdx.x;
    const float NEGINF = -__builtin_inff();
    for (int idx = t; idx < 1600; idx += 1024) {
        Tl[idx] = NEGINF; SHWl[idx] = NEGINF; REl[idx] = NEGINF;
    }
    __syncthreads();
    for (int p = t; p < NPAIR; p += 1024) {
        int i = 0, rem = p, len = L_SEQ - 1;
        while (rem >= len) { rem -= len; len--; i++; }
        int j = i + 1 + rem;
        int row = p * 16 + b;
        float tl = tlog[row];
        float re_v = (tl >= 0.f) ? -log1pf(__expf(-tl)) : (tl - log1pf(__expf(tl)));
        float sh_v = (tl <= 0.f) ? -log1pf(__expf(tl)) : (-tl - log1pf(__expf(-tl)));
        float wlp = glog[row] - __logf(rowsum[row]);
        SHWl[i * 40 + j] = sh_v + wlp;
        REl[i * 40 + j] = re_v;
    }
    if (t == 0) {
        int row = NPAIR * 16 + b;           // init cell
        Tl[0 * 40 + 1] = glog[row] - __logf(rowsum[row]);
    }
    if (t >= 1 && t <= 38) Tl[t * 40 + t + 1] = 0.f;
    __syncthreads();
    const int tg = t >> 4, li = t & 15;
    for (int gap = 2; gap <= L_SEQ - 1; gap++) {
        int n_i = L_SEQ - gap;
        float m = NEGINF, s = 0.f;
        int i = tg, j = tg + gap;
        if (tg < n_i) {
            for (int k = i + 1 + li; k < j; k += 16) {
                float v = Tl[i * 40 + k] + Tl[k * 40 + j]
                        + SHWl[i * 40 + k] + REl[k * 40 + j];
                if (v > m) { s = s * __expf(m - v) + 1.f; m = v; }
                else s += __expf(v - m);
            }
        }
#pragma unroll
        for (int off = 1; off < 16; off <<= 1) {
            float mo = __shfl_xor(m, off), so = __shfl_xor(s, off);
            float M = fmaxf(m, mo);
            float sn = 0.f;
            if (m > NEGINF) sn += s * __expf(m - M);
            if (mo > NEGINF) sn += so * __expf(mo - M);
            m = M; s = sn;
        }
        if (tg < n_i && li == 0) Tl[i * 40 + j] = m + __logf(s);
        __syncthreads();
    }
    if (t == 0) out[b] = Tl[39];
}

// ---------------------------------------------------------------------------
extern "C" void kernel_launch(void* const* d_in, const int* in_sizes, int n_in,
                              void* d_out, int out_size, void* d_ws, size_t ws_size,
                              hipStream_t stream) {
    const float* h        = (const float*)d_in[0];
    const int*   sentence = (const int*)d_in[1];
    const float* Wt1      = (const float*)d_in[2];
    const float* bt1      = (const float*)d_in[3];
    const float* Wt2      = (const float*)d_in[4];
    const float* bt2      = (const float*)d_in[5];
    const float* Ww1      = (const float*)d_in[6];
    const float* bw1      = (const float*)d_in[7];
    const float* Ww2      = (const float*)d_in[8];
    const float* bw2      = (const float*)d_in[9];
    float* out = (float*)d_out;

    char* ws = (char*)d_ws;
    size_t off = 0;
    float* UV = (float*)(ws + off);                    off += 4ull * 640 * 256 * 4;
    unsigned char* X = (unsigned char*)(ws + off);     off += (size_t)M_ROWS * 256;
    unsigned char* WbT = (unsigned char*)(ws + off);   off += (size_t)V_PAD * 256;
    float* WwT = (float*)(ws + off);                   off += (size_t)V_PAD * 256 * 4;
    float* rowsum = (float*)(ws + off);                off += (size_t)M_ROWS * 4;
    float* tlog = (float*)(ws + off);                  off += (size_t)M_ROWS * 4;
    float* glog = (float*)(ws + off);                  off += (size_t)M_ROWS * 4;

    hipMemsetAsync(rowsum, 0, (size_t)M_ROWS * 4, stream);
    prep_kernel<<<960, 256, 0, stream>>>(Ww2, WwT, WbT, h, Wt1, Ww1, UV);
    build_rows<<<M_ROWS / 4, 256, 0, stream>>>(UV, sentence, bt1, bw1, Wt2, bt2,
                                               WwT, bw2, X, tlog, glog);
    big_gemm<<<dim3(5, 49), 512, 0, stream>>>(X, WbT, bw2, rowsum);
    dp_kernel<<<16, 1024, 0, stream>>>(tlog, glog, rowsum, out);
}

// Round 13
// 193.525 us; speedup vs baseline: 2.0314x; 1.0279x over previous
//
#include <hip/hip_runtime.h>
#include <hip/hip_bf16.h>

#define L_SEQ 40
#define B_SZ  16
#define V_SZ  10000
#define V_PAD 10240
#define NPAIR 780
#define NROWP 784                 // 780 pairs + 1 init row + 3 pad "pairs"
#define M_ROWS (NROWP * B_SZ)     // 12544 rows = 49 strips of 256

typedef __attribute__((ext_vector_type(4))) float f32x4;
typedef __attribute__((ext_vector_type(4))) int   i32x4;
typedef __attribute__((ext_vector_type(8))) int   i32x8;

// ---------------------------------------------------------------------------
// float -> OCP e4m3fn. Prefer HW cvt; hand-rolled RNE fallback.
// ---------------------------------------------------------------------------
#if __has_builtin(__builtin_amdgcn_cvt_pk_fp8_f32)
__device__ __forceinline__ unsigned int pack4_fp8(float x0, float x1, float x2, float x3) {
    int lo = __builtin_amdgcn_cvt_pk_fp8_f32(x0, x1, 0, false);
    int full = __builtin_amdgcn_cvt_pk_fp8_f32(x2, x3, lo, true);
    return (unsigned int)full;
}
#else
__device__ __forceinline__ unsigned char f2e4m3(float f) {
    unsigned u = __float_as_uint(f);
    unsigned s = (u >> 24) & 0x80u;
    if ((u & 0x7FFFFFFFu) == 0) return (unsigned char)s;
    int E = (int)((u >> 23) & 0xFF) - 127 + 7;
    unsigned m = u & 0x7FFFFFu;
    if (E >= 16) return (unsigned char)(s | 0x7E);
    if (E >= 1) {
        unsigned keep = m >> 20, rest = m & 0xFFFFFu;
        keep += (rest > 0x80000u) || (rest == 0x80000u && (keep & 1));
        if (keep == 8) { keep = 0; E++; if (E >= 16) return (unsigned char)(s | 0x7E); }
        return (unsigned char)(s | (E << 3) | keep);
    }
    int shift = 1 - E;
    if (shift > 10) return (unsigned char)s;
    unsigned full = 0x800000u | m;
    unsigned sh = 20 + shift;
    unsigned keep = full >> sh, rem = full & ((1u << sh) - 1), half = 1u << (sh - 1);
    keep += (rem > half) || (rem == half && (keep & 1));
    if (keep >= 8) return (unsigned char)(s | (1 << 3));
    return (unsigned char)(s | keep);
}
__device__ __forceinline__ unsigned int pack4_fp8(float x0, float x1, float x2, float x3) {
    return (unsigned int)f2e4m3(x0) | ((unsigned int)f2e4m3(x1) << 8)
         | ((unsigned int)f2e4m3(x2) << 16) | ((unsigned int)f2e4m3(x3) << 24);
}
#endif

// 2^x via compiler-managed hardware exp (v_exp_f32 is base-2)
#if __has_builtin(__builtin_amdgcn_exp2f)
__device__ __forceinline__ float exp2_hw(float x) { return __builtin_amdgcn_exp2f(x); }
#else
__device__ __forceinline__ float exp2_hw(float x) { return __expf(x * 0.6931471805599453f); }
#endif

#if __has_builtin(__builtin_amdgcn_rcpf)
__device__ __forceinline__ float rcp_hw(float x) { return __builtin_amdgcn_rcpf(x); }
#else
__device__ __forceinline__ float rcp_hw(float x) { return 1.0f / x; }
#endif

// tanh(x) = 1 - 2/(e^{2x}+1): exp2 + add + rcp + fma = 5 VALU ops vs ~30 for
// ocml tanhf. Exact at +/-inf saturation; |err| ~1e-6 (rcp is ~1 ulp).
__device__ __forceinline__ float fast_tanh(float x) {
    float e = exp2_hw(x * 2.885390081777926814f);   // 2*log2(e)
    return fmaf(-2.0f, rcp_hw(e + 1.0f), 1.0f);
}

// Layout note: X and WbT are PLAIN row-major fp8 [row][k], 256 B per row.
// The MX-scaled MFMA (16x16x128) fragment is linear per lane: lane l holds
// row l&15, K-bytes (l>>4)*32 .. +31 — no byte permutation needed.

// ---------------------------------------------------------------------------
// K1: fused prep (round-9 re-tile).
// ---------------------------------------------------------------------------
__global__ __launch_bounds__(256) void prep_kernel(
        const float* __restrict__ Ww2, float* __restrict__ WwT,
        unsigned char* __restrict__ WbT,
        const float* __restrict__ h, const float* __restrict__ Wt1,
        const float* __restrict__ Ww1, float* __restrict__ UV) {
    const int bx = blockIdx.x;
    const int t = threadIdx.x;
    __shared__ float smem[32 * 132];             // union: tile[32][132] / hs[8*512]
    if (bx < 640) {
        // ---- transpose block: 32 k x 128 v
        float (*tile)[132] = (float (*)[132])smem;
        int v0 = (bx % 80) * 128;
        int k0 = (bx / 80) * 32;
        int tx4 = t & 31, ky = t >> 5;           // float4 col, 8 rows/pass
        int v = v0 + tx4 * 4;
#pragma unroll
        for (int r = 0; r < 4; r++) {
            int k = k0 + ky + r * 8;
            float4 val = make_float4(0.f, 0.f, 0.f, 0.f);
            if (v < V_SZ) val = *(const float4*)(Ww2 + (size_t)k * V_SZ + v);
            *(float4*)(&tile[ky + r * 8][tx4 * 4]) = val;
        }
        __syncthreads();
        int kx4 = t & 7, vr8 = t >> 3;           // 8 float4 per 32 k, 32 v/pass
#pragma unroll
        for (int pass = 0; pass < 4; pass++) {
            int vr = vr8 + pass * 32;
            float c0 = tile[kx4 * 4 + 0][vr];
            float c1 = tile[kx4 * 4 + 1][vr];
            float c2 = tile[kx4 * 4 + 2][vr];
            float c3 = tile[kx4 * 4 + 3][vr];
            float4 cv = make_float4(c0, c1, c2, c3);
            *(float4*)(WwT + (size_t)(v0 + vr) * 256 + k0 + kx4 * 4) = cv;
            ((unsigned int*)WbT)[(size_t)(v0 + vr) * 64 + (k0 >> 2) + kx4] =
                pack4_fp8(c0, c1, c2, c3);
        }
    } else {
        // ---- UV block: 8 h-rows x 256 cols of one weight half
        float* hs = smem;                        // 8*512 floats = 16 KB
        int ub = bx - 640;
        int which = ub / 80;         // 0:Ut 1:Vt 2:Uw 3:Vw
        int m0 = (ub % 80) * 8;
        const float4* src = (const float4*)(h + (size_t)m0 * 512);
        float4* dst4 = (float4*)hs;
#pragma unroll
        for (int v = 0; v < 4; v++) dst4[v * 256 + t] = src[v * 256 + t];
        __syncthreads();
        const float* W = ((which < 2) ? Wt1 : Ww1) + ((which & 1) ? 512 * 256 : 0);
        float acc[8] = {};
        for (int f = 0; f < 512; f += 4) {
            float w0 = W[(f + 0) * 256 + t];
            float w1 = W[(f + 1) * 256 + t];
            float w2 = W[(f + 2) * 256 + t];
            float w3 = W[(f + 3) * 256 + t];
#pragma unroll
            for (int r = 0; r < 8; r++) {
                float4 hv = *(const float4*)(hs + r * 512 + f);
                acc[r] += hv.x * w0 + hv.y * w1 + hv.z * w2 + hv.w * w3;
            }
        }
        float* dst = UV + ((size_t)which * 640 + m0) * 256;
#pragma unroll
        for (int r = 0; r < 8; r++) dst[r * 256 + t] = acc[r];
    }
}

// ---------------------------------------------------------------------------
// K2: per (pair,b) row: X = fp8(tanh(Uw[i]+Vw[j]+bw1)) linear row-major;
//     tlog/glog fp32 exact. One wave per row; p==780 is the init cell.
// ---------------------------------------------------------------------------
__global__ void build_rows(const float* __restrict__ UV,
                           const int* __restrict__ sentence,
                           const float* __restrict__ bt1,
                           const float* __restrict__ bw1,
                           const float* __restrict__ Wt2,
                           const float* __restrict__ bt2,
                           const float* __restrict__ WwT,
                           const float* __restrict__ bw2,
                           unsigned char* __restrict__ X,
                           float* __restrict__ tlog,
                           float* __restrict__ glog) {
    int w = blockIdx.x * 4 + (threadIdx.x >> 6);
    int lane = threadIdx.x & 63;
    int p = w >> 4, b = w & 15;
    int i = 0, j = 0;
    if (p < NPAIR) {
        int rem = p, len = L_SEQ - 1;
        while (rem >= len) { rem -= len; len--; i++; }
        j = i + 1 + rem;
    }
    int j1 = (j + 1 < L_SEQ) ? j + 1 : L_SEQ - 1;
    int tgt = sentence[j1 * B_SZ + b];
    const float4 ut = ((const float4*)(UV + 0 * 640 * 256 + (i * B_SZ + b) * 256))[lane];
    const float4 vt = ((const float4*)(UV + 1 * 640 * 256 + (j * B_SZ + b) * 256))[lane];
    const float4 uw = ((const float4*)(UV + 2 * 640 * 256 + (i * B_SZ + b) * 256))[lane];
    const float4 vw = ((const float4*)(UV + 3 * 640 * 256 + (j * B_SZ + b) * 256))[lane];
    const float4 bt = ((const float4*)bt1)[lane];
    const float4 bw = ((const float4*)bw1)[lane];
    const float4 w2 = ((const float4*)Wt2)[lane];
    const float4 wc = ((const float4*)(WwT + (size_t)tgt * 256))[lane];
    float xt0 = fast_tanh(ut.x + vt.x + bt.x), xt1 = fast_tanh(ut.y + vt.y + bt.y);
    float xt2 = fast_tanh(ut.z + vt.z + bt.z), xt3 = fast_tanh(ut.w + vt.w + bt.w);
    float xw0 = fast_tanh(uw.x + vw.x + bw.x), xw1 = fast_tanh(uw.y + vw.y + bw.y);
    float xw2 = fast_tanh(uw.z + vw.z + bw.z), xw3 = fast_tanh(uw.w + vw.w + bw.w);
    // linear: lane covers k = 4*lane .. 4*lane+3
    ((unsigned int*)X)[w * 64 + lane] = pack4_fp8(xw0, xw1, xw2, xw3);
    float td = xt0 * w2.x + xt1 * w2.y + xt2 * w2.z + xt3 * w2.w;
    float gd = xw0 * wc.x + xw1 * wc.y + xw2 * wc.z + xw3 * wc.w;
#pragma unroll
    for (int off = 32; off >= 1; off >>= 1) {
        td += __shfl_xor(td, off);
        gd += __shfl_xor(gd, off);
    }
    if (lane == 0) {
        tlog[w] = td + bt2[0];
        glog[w] = gd + bw2[tgt];
    }
}

// ---------------------------------------------------------------------------
// K3: MX-scaled fp8 GEMM (16x16x128, unit scales) + fused sum-exp.
// Round-12 re-decomposition (lesson: per-iter cycle audit showed the old
// 8x(32rx64c) layout read every B column from LDS 8x -> LDS pipe was the
// largest wall (1536 cy/iter/CU) and phases ran serialized (4400 cy/iter)):
//  * 8 waves = 4 row-groups x 2 col-halves; wave = 64 rows x 64 cols.
//    Each B byte now read by 4 waves (LDS traffic per column HALVED).
//  * Iteration = 128 cols, NIT = 16: sync/loop overhead count halved.
//    LDS = 3 x 32 KB + 8 KB bias = 104 KB -> 1 block/CU, 245 blocks.
//  * Per-ni interleaved epilogue: after a col-group's kb=1 MFMAs, its 16
//    exp2s issue while the next group's MFMAs occupy the matrix pipe
//    (trans and matrix pipes are separate).
//  * Single reused br[8] read buffer keeps regs ~216 < 256 (no spill;
//    watch WRITE_SIZE).
// Schedule per iter (race-fixed, round-8): vmcnt(0) [DMA issued a full
// iter ago, ~free] -> barrier -> issue DMA it+2 -> compute.
// ---------------------------------------------------------------------------
#define RD8(BASE, KB, BR) \
    BR[0] = *(const i32x4*)((BASE) + offs[(KB)*8 + 0]); \
    BR[1] = *(const i32x4*)((BASE) + offs[(KB)*8 + 1]); \
    BR[2] = *(const i32x4*)((BASE) + offs[(KB)*8 + 2]); \
    BR[3] = *(const i32x4*)((BASE) + offs[(KB)*8 + 3]); \
    BR[4] = *(const i32x4*)((BASE) + offs[(KB)*8 + 4]); \
    BR[5] = *(const i32x4*)((BASE) + offs[(KB)*8 + 5]); \
    BR[6] = *(const i32x4*)((BASE) + offs[(KB)*8 + 6]); \
    BR[7] = *(const i32x4*)((BASE) + offs[(KB)*8 + 7]);

#define MF4(KB, NI, BR) { \
    i32x8 bv_ = __builtin_shufflevector(BR[2*(NI)], BR[2*(NI)+1], 0,1,2,3,4,5,6,7); \
    acc[0][NI] = __builtin_amdgcn_mfma_scale_f32_16x16x128_f8f6f4( \
        apan[0][KB], bv_, acc[0][NI], 0,0, 0,0x7F7F7F7F, 0,0x7F7F7F7F); \
    acc[1][NI] = __builtin_amdgcn_mfma_scale_f32_16x16x128_f8f6f4( \
        apan[1][KB], bv_, acc[1][NI], 0,0, 0,0x7F7F7F7F, 0,0x7F7F7F7F); \
    acc[2][NI] = __builtin_amdgcn_mfma_scale_f32_16x16x128_f8f6f4( \
        apan[2][KB], bv_, acc[2][NI], 0,0, 0,0x7F7F7F7F, 0,0x7F7F7F7F); \
    acc[3][NI] = __builtin_amdgcn_mfma_scale_f32_16x16x128_f8f6f4( \
        apan[3][KB], bv_, acc[3][NI], 0,0, 0,0x7F7F7F7F, 0,0x7F7F7F7F); \
}

#define EPI(NI) { \
    float bL_ = bl[NI]; \
    _Pragma("unroll") \
    for (int mi_ = 0; mi_ < 4; mi_++) \
        _Pragma("unroll") \
        for (int r_ = 0; r_ < 4; r_++) \
            PS[mi_][r_] += exp2_hw(fmaf(acc[mi_][NI][r_], L2E, bL_)); \
}

__global__ __launch_bounds__(512, 2) void big_gemm(
        const unsigned char* __restrict__ X,
        const unsigned char* __restrict__ WbT,
        const float* __restrict__ bw2,
        float* __restrict__ rowsum) {
    __shared__ unsigned char Bs[3][128 * 256];   // 3 x 32 KB
    __shared__ float biasL[2048];                // bw2*log2e for this col group
    const int t = threadIdx.x;
    const int wid = t >> 6, lane = t & 63;
    const int l15 = lane & 15, l4 = lane >> 4;
    const int rg = wid >> 1, ch = wid & 1;       // row-group / col-half
    const int g = blockIdx.x;                    // col group: 2048 cols
    const int row0 = blockIdx.y * 256 + rg * 64;
    const int NIT = 16;                          // 16 x 128 cols
    const float L2E = 1.44269504088896340736f;

    // ---- stage bias into LDS (prologue VMEM only)
#pragma unroll
    for (int k = 0; k < 4; k++) {
        int idx = k * 512 + t;
        int col = g * 2048 + idx;
        biasL[idx] = (col < V_SZ) ? bw2[col] * L2E : -__builtin_inff();
    }

    // ---- hoisted swizzled LDS byte offsets: (kb, ni, gg)
    int offs[16];
#pragma unroll
    for (int kb = 0; kb < 2; kb++)
#pragma unroll
        for (int ni = 0; ni < 4; ni++)
#pragma unroll
            for (int gg = 0; gg < 2; gg++) {
                int cc = ch * 64 + ni * 16 + l15;   // col within 128-col tile
                int gr = kb * 8 + l4 * 2 + gg;      // granule within row
                offs[kb * 8 + ni * 2 + gg] = cc * 256 + ((gr ^ (cc & 15)) << 4);
            }

    // 8 waves x 4 loads x 64 lanes x 16 B = 32 KB tile
    auto dmaB = [&](int buf, int it) {
        const unsigned char* Bg = WbT + (size_t)(g * 2048 + it * 128) * 256;
#pragma unroll
        for (int q = 0; q < 4; q++) {
            int off = (wid * 4 + q) * 1024;      // wave-uniform dest (in tile)
            int F = off + lane * 16;             // this lane's dest byte
            int cc = F >> 8;                     // dest col within tile
            int s = (F >> 4) & 15;               // dest granule slot
            int srcg = s ^ (cc & 15);            // swizzled source granule
            __builtin_amdgcn_global_load_lds(
                (const __attribute__((address_space(1))) unsigned int*)(Bg + cc * 256 + (srcg << 4)),
                (__attribute__((address_space(3))) unsigned int*)(&Bs[buf][0] + off),
                16, 0, 0);
        }
    };

    dmaB(0, 0);
    // ---- A panel: 64 rows x K=256 in 64 VGPRs (linear, 32 B/lane/block)
    i32x8 apan[4][2];
    {
        const unsigned char* Ag = X + (size_t)row0 * 256;
#pragma unroll
        for (int mi = 0; mi < 4; mi++)
#pragma unroll
            for (int kb = 0; kb < 2; kb++)
                apan[mi][kb] = *(const i32x8*)(Ag + (mi * 16 + l15) * 256 + kb * 128 + l4 * 32);
    }
    dmaB(1, 1);
    __syncthreads();             // one-time full drain: tile0, tile1, A, bias

    float PS[4][4] = {};
    int bc = 0, bp = 2;          // current / dma-target buffer indices

#pragma unroll 1
    for (int it = 0; it < NIT; it++) {
        // tile it+1 (issued one full iteration ago) retires ~free; barrier
        // THEN dma keeps the buffer-reuse WAR ordered.
        asm volatile("s_waitcnt vmcnt(0)" ::: "memory");
        __builtin_amdgcn_s_barrier();
        if (it + 2 < NIT) dmaB(bp, it + 2);
        const unsigned char* bufC = &Bs[bc][0];
        float bl[4];
#pragma unroll
        for (int ni = 0; ni < 4; ni++)
            bl[ni] = biasL[it * 128 + ch * 64 + ni * 16 + l15];
        f32x4 acc[4][4] = {};
        i32x4 br[8];
        __builtin_amdgcn_s_setprio(1);
        // ---- kb = 0: 8 reads, 16 MFMAs
        RD8(bufC, 0, br);
        MF4(0, 0, br); MF4(0, 1, br); MF4(0, 2, br); MF4(0, 3, br);
        // ---- kb = 1: 8 reads (reuse br), then per-ni MFMAs + interleaved
        //      epilogue: exp2(ni) runs on trans pipe while MFMAs(ni+1) run
        //      on the matrix pipe.
        RD8(bufC, 1, br);
        MF4(1, 0, br);
        MF4(1, 1, br); EPI(0);
        MF4(1, 2, br); EPI(1);
        MF4(1, 3, br); EPI(2);
        __builtin_amdgcn_s_setprio(0);
        EPI(3);
        bc = (bc == 2) ? 0 : bc + 1;
        bp = (bp == 2) ? 0 : bp + 1;
    }
    // ---- one butterfly + atomics per wave ----
#pragma unroll
    for (int mi = 0; mi < 4; mi++)
#pragma unroll
        for (int r = 0; r < 4; r++) {
            float v = PS[mi][r];
            v += __shfl_xor(v, 1); v += __shfl_xor(v, 2);
            v += __shfl_xor(v, 4); v += __shfl_xor(v, 8);
            if (l15 == 0)
                atomicAdd(&rowsum[row0 + mi * 16 + l4 * 4 + r], v);
        }
}

// ---------------------------------------------------------------------------
// K4: build tables in LDS + CKY DP. 16 blocks (one per batch), 1024 thr,
// 16 lanes per (i) cell parallelize the split loop.
// ---------------------------------------------------------------------------
__global__ __launch_bounds__(1024) void dp_kernel(const float* __restrict__ tlog,
                          const float* __restrict__ glog,
                          const float* __restrict__ rowsum,
                          float* __restrict__ out) {
    __shared__ float Tl[1600], SHWl[1600], REl[1600];
    const int t = threadIdx.x;
    const int b = blockIdx.x;
    const float NEGINF = -__builtin_inff();
    for (int idx = t; idx < 1600; idx += 1024) {
        Tl[idx] = NEGINF; SHWl[idx] = NEGINF; REl[idx] = NEGINF;
    }
    __syncthreads();
    for (int p = t; p < NPAIR; p += 1024) {
        int i = 0, rem = p, len = L_SEQ - 1;
        while (rem >= len) { rem -= len; len--; i++; }
        int j = i + 1 + rem;
        int row = p * 16 + b;
        float tl = tlog[row];
        float re_v = (tl >= 0.f) ? -log1pf(__expf(-tl)) : (tl - log1pf(__expf(tl)));
        float sh_v = (tl <= 0.f) ? -log1pf(__expf(tl)) : (-tl - log1pf(__expf(-tl)));
        float wlp = glog[row] - __logf(rowsum[row]);
        SHWl[i * 40 + j] = sh_v + wlp;
        REl[i * 40 + j] = re_v;
    }
    if (t == 0) {
        int row = NPAIR * 16 + b;           // init cell
        Tl[0 * 40 + 1] = glog[row] - __logf(rowsum[row]);
    }
    if (t >= 1 && t <= 38) Tl[t * 40 + t + 1] = 0.f;
    __syncthreads();
    const int tg = t >> 4, li = t & 15;
    for (int gap = 2; gap <= L_SEQ - 1; gap++) {
        int n_i = L_SEQ - gap;
        float m = NEGINF, s = 0.f;
        int i = tg, j = tg + gap;
        if (tg < n_i) {
            for (int k = i + 1 + li; k < j; k += 16) {
                float v = Tl[i * 40 + k] + Tl[k * 40 + j]
                        + SHWl[i * 40 + k] + REl[k * 40 + j];
                if (v > m) { s = s * __expf(m - v) + 1.f; m = v; }
                else s += __expf(v - m);
            }
        }
#pragma unroll
        for (int off = 1; off < 16; off <<= 1) {
            float mo = __shfl_xor(m, off), so = __shfl_xor(s, off);
            float M = fmaxf(m, mo);
            float sn = 0.f;
            if (m > NEGINF) sn += s * __expf(m - M);
            if (mo > NEGINF) sn += so * __expf(mo - M);
            m = M; s = sn;
        }
        if (tg < n_i && li == 0) Tl[i * 40 + j] = m + __logf(s);
        __syncthreads();
    }
    if (t == 0) out[b] = Tl[39];
}

// ---------------------------------------------------------------------------
extern "C" void kernel_launch(void* const* d_in, const int* in_sizes, int n_in,
                              void* d_out, int out_size, void* d_ws, size_t ws_size,
                              hipStream_t stream) {
    const float* h        = (const float*)d_in[0];
    const int*   sentence = (const int*)d_in[1];
    const float* Wt1      = (const float*)d_in[2];
    const float* bt1      = (const float*)d_in[3];
    const float* Wt2      = (const float*)d_in[4];
    const float* bt2      = (const float*)d_in[5];
    const float* Ww1      = (const float*)d_in[6];
    const float* bw1      = (const float*)d_in[7];
    const float* Ww2      = (const float*)d_in[8];
    const float* bw2      = (const float*)d_in[9];
    float* out = (float*)d_out;

    char* ws = (char*)d_ws;
    size_t off = 0;
    float* UV = (float*)(ws + off);                    off += 4ull * 640 * 256 * 4;
    unsigned char* X = (unsigned char*)(ws + off);     off += (size_t)M_ROWS * 256;
    unsigned char* WbT = (unsigned char*)(ws + off);   off += (size_t)V_PAD * 256;
    float* WwT = (float*)(ws + off);                   off += (size_t)V_PAD * 256 * 4;
    float* rowsum = (float*)(ws + off);                off += (size_t)M_ROWS * 4;
    float* tlog = (float*)(ws + off);                  off += (size_t)M_ROWS * 4;
    float* glog = (float*)(ws + off);                  off += (size_t)M_ROWS * 4;

    hipMemsetAsync(rowsum, 0, (size_t)M_ROWS * 4, stream);
    prep_kernel<<<960, 256, 0, stream>>>(Ww2, WwT, WbT, h, Wt1, Ww1, UV);
    build_rows<<<M_ROWS / 4, 256, 0, stream>>>(UV, sentence, bt1, bw1, Wt2, bt2,
                                               WwT, bw2, X, tlog, glog);
    big_gemm<<<dim3(5, 49), 512, 0, stream>>>(X, WbT, bw2, rowsum);
    dp_kernel<<<16, 1024, 0, stream>>>(tlog, glog, rowsum, out);
}

// Round 14
// 181.739 us; speedup vs baseline: 2.1632x; 1.0648x over previous
//
#include <hip/hip_runtime.h>
#include <hip/hip_bf16.h>

#define L_SEQ 40
#define B_SZ  16
#define V_SZ  10000
#define V_PAD 10240
#define NPAIR 780
#define NROWP 784                 // 780 pairs + 1 init row + 3 pad "pairs"
#define M_ROWS (NROWP * B_SZ)     // 12544 rows = 49 strips of 256

typedef __attribute__((ext_vector_type(4))) float f32x4;
typedef __attribute__((ext_vector_type(4))) int   i32x4;
typedef __attribute__((ext_vector_type(8))) int   i32x8;

// ---------------------------------------------------------------------------
// float -> OCP e4m3fn. Prefer HW cvt; hand-rolled RNE fallback.
// ---------------------------------------------------------------------------
#if __has_builtin(__builtin_amdgcn_cvt_pk_fp8_f32)
__device__ __forceinline__ unsigned int pack4_fp8(float x0, float x1, float x2, float x3) {
    int lo = __builtin_amdgcn_cvt_pk_fp8_f32(x0, x1, 0, false);
    int full = __builtin_amdgcn_cvt_pk_fp8_f32(x2, x3, lo, true);
    return (unsigned int)full;
}
#else
__device__ __forceinline__ unsigned char f2e4m3(float f) {
    unsigned u = __float_as_uint(f);
    unsigned s = (u >> 24) & 0x80u;
    if ((u & 0x7FFFFFFFu) == 0) return (unsigned char)s;
    int E = (int)((u >> 23) & 0xFF) - 127 + 7;
    unsigned m = u & 0x7FFFFFu;
    if (E >= 16) return (unsigned char)(s | 0x7E);
    if (E >= 1) {
        unsigned keep = m >> 20, rest = m & 0xFFFFFu;
        keep += (rest > 0x80000u) || (rest == 0x80000u && (keep & 1));
        if (keep == 8) { keep = 0; E++; if (E >= 16) return (unsigned char)(s | 0x7E); }
        return (unsigned char)(s | (E << 3) | keep);
    }
    int shift = 1 - E;
    if (shift > 10) return (unsigned char)s;
    unsigned full = 0x800000u | m;
    unsigned sh = 20 + shift;
    unsigned keep = full >> sh, rem = full & ((1u << sh) - 1), half = 1u << (sh - 1);
    keep += (rem > half) || (rem == half && (keep & 1));
    if (keep >= 8) return (unsigned char)(s | (1 << 3));
    return (unsigned char)(s | keep);
}
__device__ __forceinline__ unsigned int pack4_fp8(float x0, float x1, float x2, float x3) {
    return (unsigned int)f2e4m3(x0) | ((unsigned int)f2e4m3(x1) << 8)
         | ((unsigned int)f2e4m3(x2) << 16) | ((unsigned int)f2e4m3(x3) << 24);
}
#endif

// 2^x via compiler-managed hardware exp (v_exp_f32 is base-2)
#if __has_builtin(__builtin_amdgcn_exp2f)
__device__ __forceinline__ float exp2_hw(float x) { return __builtin_amdgcn_exp2f(x); }
#else
__device__ __forceinline__ float exp2_hw(float x) { return __expf(x * 0.6931471805599453f); }
#endif

#if __has_builtin(__builtin_amdgcn_rcpf)
__device__ __forceinline__ float rcp_hw(float x) { return __builtin_amdgcn_rcpf(x); }
#else
__device__ __forceinline__ float rcp_hw(float x) { return 1.0f / x; }
#endif

// tanh(x) = 1 - 2/(e^{2x}+1): exp2 + add + rcp + fma = 5 VALU ops vs ~30 for
// ocml tanhf. Exact at +/-inf saturation; |err| ~1e-6 (rcp is ~1 ulp).
__device__ __forceinline__ float fast_tanh(float x) {
    float e = exp2_hw(x * 2.885390081777926814f);   // 2*log2(e)
    return fmaf(-2.0f, rcp_hw(e + 1.0f), 1.0f);
}

// Layout note: X and WbT are PLAIN row-major fp8 [row][k], 256 B per row.
// The MX-scaled MFMA (16x16x128) fragment is linear per lane: lane l holds
// row l&15, K-bytes (l>>4)*32 .. +31 — no byte permutation needed.

// ---------------------------------------------------------------------------
// K1: fused prep. Round-14 fix (round-13 profile: UV half = 320 blocks each
// serially walking K=512 with L2-latency-exposed W loads ~11 us/block ->
// 2 ragged rounds = 49 us; transpose half was fine):
//  * UV is K-SPLIT x4: 1280 blocks, each K=128 (32 load iterations ~2.7 us),
//    accumulating with fp32 atomicAdd into memset-zeroed UV. Grid = 1920
//    short mixed blocks -> latency hidden by block-level TLP.
//  * Transpose: unchanged (640 blocks, float4 both directions).
// ---------------------------------------------------------------------------
__global__ __launch_bounds__(256) void prep_kernel(
        const float* __restrict__ Ww2, float* __restrict__ WwT,
        unsigned char* __restrict__ WbT,
        const float* __restrict__ h, const float* __restrict__ Wt1,
        const float* __restrict__ Ww1, float* __restrict__ UV) {
    const int bx = blockIdx.x;
    const int t = threadIdx.x;
    __shared__ float smem[32 * 132];             // union: tile[32][132] / hs[8*128]
    if (bx < 640) {
        // ---- transpose block: 32 k x 128 v
        float (*tile)[132] = (float (*)[132])smem;
        int v0 = (bx % 80) * 128;
        int k0 = (bx / 80) * 32;
        int tx4 = t & 31, ky = t >> 5;           // float4 col, 8 rows/pass
        int v = v0 + tx4 * 4;
#pragma unroll
        for (int r = 0; r < 4; r++) {
            int k = k0 + ky + r * 8;
            float4 val = make_float4(0.f, 0.f, 0.f, 0.f);
            if (v < V_SZ) val = *(const float4*)(Ww2 + (size_t)k * V_SZ + v);
            *(float4*)(&tile[ky + r * 8][tx4 * 4]) = val;
        }
        __syncthreads();
        int kx4 = t & 7, vr8 = t >> 3;           // 8 float4 per 32 k, 32 v/pass
#pragma unroll
        for (int pass = 0; pass < 4; pass++) {
            int vr = vr8 + pass * 32;
            float c0 = tile[kx4 * 4 + 0][vr];
            float c1 = tile[kx4 * 4 + 1][vr];
            float c2 = tile[kx4 * 4 + 2][vr];
            float c3 = tile[kx4 * 4 + 3][vr];
            float4 cv = make_float4(c0, c1, c2, c3);
            *(float4*)(WwT + (size_t)(v0 + vr) * 256 + k0 + kx4 * 4) = cv;
            ((unsigned int*)WbT)[(size_t)(v0 + vr) * 64 + (k0 >> 2) + kx4] =
                pack4_fp8(c0, c1, c2, c3);
        }
    } else {
        // ---- UV block: 8 h-rows x 256 cols x K-chunk of 128
        float* hs = smem;                        // 8*128 floats = 4 KB
        int ub = bx - 640;                       // 0..1279
        int which = ub >> 8;                     // ub / 320 ... careful below
        which = ub / 320;                        // 0:Ut 1:Vt 2:Uw 3:Vw
        int rem = ub - which * 320;
        int m0 = (rem >> 2) * 8;                 // 80 row-groups
        int ks = rem & 3;                        // K-chunk 0..3
        int f0 = ks * 128;
        // stage 8 rows x 128 f of h: 1024 floats = 256 float4, 1/thread
        {
            int r = t >> 5, fq = t & 31;
            ((float4*)hs)[r * 32 + fq] =
                *(const float4*)(h + (size_t)(m0 + r) * 512 + f0 + fq * 4);
        }
        __syncthreads();
        const float* W = ((which < 2) ? Wt1 : Ww1)
                       + ((which & 1) ? 512 * 256 : 0) + (size_t)f0 * 256;
        float acc[8] = {};
        for (int f = 0; f < 128; f += 4) {
            float w0 = W[(f + 0) * 256 + t];
            float w1 = W[(f + 1) * 256 + t];
            float w2 = W[(f + 2) * 256 + t];
            float w3 = W[(f + 3) * 256 + t];
#pragma unroll
            for (int r = 0; r < 8; r++) {
                float4 hv = *(const float4*)(hs + r * 128 + f);
                acc[r] += hv.x * w0 + hv.y * w1 + hv.z * w2 + hv.w * w3;
            }
        }
        float* dst = UV + ((size_t)which * 640 + m0) * 256;
#pragma unroll
        for (int r = 0; r < 8; r++) atomicAdd(&dst[r * 256 + t], acc[r]);
    }
}

// ---------------------------------------------------------------------------
// K2: per (pair,b) row: X = fp8(tanh(Uw[i]+Vw[j]+bw1)) linear row-major;
//     tlog/glog fp32 exact. One wave per row; p==780 is the init cell.
// ---------------------------------------------------------------------------
__global__ void build_rows(const float* __restrict__ UV,
                           const int* __restrict__ sentence,
                           const float* __restrict__ bt1,
                           const float* __restrict__ bw1,
                           const float* __restrict__ Wt2,
                           const float* __restrict__ bt2,
                           const float* __restrict__ WwT,
                           const float* __restrict__ bw2,
                           unsigned char* __restrict__ X,
                           float* __restrict__ tlog,
                           float* __restrict__ glog) {
    int w = blockIdx.x * 4 + (threadIdx.x >> 6);
    int lane = threadIdx.x & 63;
    int p = w >> 4, b = w & 15;
    int i = 0, j = 0;
    if (p < NPAIR) {
        int rem = p, len = L_SEQ - 1;
        while (rem >= len) { rem -= len; len--; i++; }
        j = i + 1 + rem;
    }
    int j1 = (j + 1 < L_SEQ) ? j + 1 : L_SEQ - 1;
    int tgt = sentence[j1 * B_SZ + b];
    const float4 ut = ((const float4*)(UV + 0 * 640 * 256 + (i * B_SZ + b) * 256))[lane];
    const float4 vt = ((const float4*)(UV + 1 * 640 * 256 + (j * B_SZ + b) * 256))[lane];
    const float4 uw = ((const float4*)(UV + 2 * 640 * 256 + (i * B_SZ + b) * 256))[lane];
    const float4 vw = ((const float4*)(UV + 3 * 640 * 256 + (j * B_SZ + b) * 256))[lane];
    const float4 bt = ((const float4*)bt1)[lane];
    const float4 bw = ((const float4*)bw1)[lane];
    const float4 w2 = ((const float4*)Wt2)[lane];
    const float4 wc = ((const float4*)(WwT + (size_t)tgt * 256))[lane];
    float xt0 = fast_tanh(ut.x + vt.x + bt.x), xt1 = fast_tanh(ut.y + vt.y + bt.y);
    float xt2 = fast_tanh(ut.z + vt.z + bt.z), xt3 = fast_tanh(ut.w + vt.w + bt.w);
    float xw0 = fast_tanh(uw.x + vw.x + bw.x), xw1 = fast_tanh(uw.y + vw.y + bw.y);
    float xw2 = fast_tanh(uw.z + vw.z + bw.z), xw3 = fast_tanh(uw.w + vw.w + bw.w);
    // linear: lane covers k = 4*lane .. 4*lane+3
    ((unsigned int*)X)[w * 64 + lane] = pack4_fp8(xw0, xw1, xw2, xw3);
    float td = xt0 * w2.x + xt1 * w2.y + xt2 * w2.z + xt3 * w2.w;
    float gd = xw0 * wc.x + xw1 * wc.y + xw2 * wc.z + xw3 * wc.w;
#pragma unroll
    for (int off = 32; off >= 1; off >>= 1) {
        td += __shfl_xor(td, off);
        gd += __shfl_xor(gd, off);
    }
    if (lane == 0) {
        tlog[w] = td + bt2[0];
        glog[w] = gd + bw2[tgt];
    }
}

// ---------------------------------------------------------------------------
// K3: MX-scaled fp8 GEMM (16x16x128, unit scales) + fused sum-exp.
// Round-12 structure (4 row-groups x 2 col-halves, 128-col iterations,
// interleaved per-ni epilogue) — unchanged; it measured 47.4 us (was 58.8).
// ---------------------------------------------------------------------------
#define RD8(BASE, KB, BR) \
    BR[0] = *(const i32x4*)((BASE) + offs[(KB)*8 + 0]); \
    BR[1] = *(const i32x4*)((BASE) + offs[(KB)*8 + 1]); \
    BR[2] = *(const i32x4*)((BASE) + offs[(KB)*8 + 2]); \
    BR[3] = *(const i32x4*)((BASE) + offs[(KB)*8 + 3]); \
    BR[4] = *(const i32x4*)((BASE) + offs[(KB)*8 + 4]); \
    BR[5] = *(const i32x4*)((BASE) + offs[(KB)*8 + 5]); \
    BR[6] = *(const i32x4*)((BASE) + offs[(KB)*8 + 6]); \
    BR[7] = *(const i32x4*)((BASE) + offs[(KB)*8 + 7]);

#define MF4(KB, NI, BR) { \
    i32x8 bv_ = __builtin_shufflevector(BR[2*(NI)], BR[2*(NI)+1], 0,1,2,3,4,5,6,7); \
    acc[0][NI] = __builtin_amdgcn_mfma_scale_f32_16x16x128_f8f6f4( \
        apan[0][KB], bv_, acc[0][NI], 0,0, 0,0x7F7F7F7F, 0,0x7F7F7F7F); \
    acc[1][NI] = __builtin_amdgcn_mfma_scale_f32_16x16x128_f8f6f4( \
        apan[1][KB], bv_, acc[1][NI], 0,0, 0,0x7F7F7F7F, 0,0x7F7F7F7F); \
    acc[2][NI] = __builtin_amdgcn_mfma_scale_f32_16x16x128_f8f6f4( \
        apan[2][KB], bv_, acc[2][NI], 0,0, 0,0x7F7F7F7F, 0,0x7F7F7F7F); \
    acc[3][NI] = __builtin_amdgcn_mfma_scale_f32_16x16x128_f8f6f4( \
        apan[3][KB], bv_, acc[3][NI], 0,0, 0,0x7F7F7F7F, 0,0x7F7F7F7F); \
}

#define EPI(NI) { \
    float bL_ = bl[NI]; \
    _Pragma("unroll") \
    for (int mi_ = 0; mi_ < 4; mi_++) \
        _Pragma("unroll") \
        for (int r_ = 0; r_ < 4; r_++) \
            PS[mi_][r_] += exp2_hw(fmaf(acc[mi_][NI][r_], L2E, bL_)); \
}

__global__ __launch_bounds__(512, 2) void big_gemm(
        const unsigned char* __restrict__ X,
        const unsigned char* __restrict__ WbT,
        const float* __restrict__ bw2,
        float* __restrict__ rowsum) {
    __shared__ unsigned char Bs[3][128 * 256];   // 3 x 32 KB
    __shared__ float biasL[2048];                // bw2*log2e for this col group
    const int t = threadIdx.x;
    const int wid = t >> 6, lane = t & 63;
    const int l15 = lane & 15, l4 = lane >> 4;
    const int rg = wid >> 1, ch = wid & 1;       // row-group / col-half
    const int g = blockIdx.x;                    // col group: 2048 cols
    const int row0 = blockIdx.y * 256 + rg * 64;
    const int NIT = 16;                          // 16 x 128 cols
    const float L2E = 1.44269504088896340736f;

    // ---- stage bias into LDS (prologue VMEM only)
#pragma unroll
    for (int k = 0; k < 4; k++) {
        int idx = k * 512 + t;
        int col = g * 2048 + idx;
        biasL[idx] = (col < V_SZ) ? bw2[col] * L2E : -__builtin_inff();
    }

    // ---- hoisted swizzled LDS byte offsets: (kb, ni, gg)
    int offs[16];
#pragma unroll
    for (int kb = 0; kb < 2; kb++)
#pragma unroll
        for (int ni = 0; ni < 4; ni++)
#pragma unroll
            for (int gg = 0; gg < 2; gg++) {
                int cc = ch * 64 + ni * 16 + l15;   // col within 128-col tile
                int gr = kb * 8 + l4 * 2 + gg;      // granule within row
                offs[kb * 8 + ni * 2 + gg] = cc * 256 + ((gr ^ (cc & 15)) << 4);
            }

    // 8 waves x 4 loads x 64 lanes x 16 B = 32 KB tile
    auto dmaB = [&](int buf, int it) {
        const unsigned char* Bg = WbT + (size_t)(g * 2048 + it * 128) * 256;
#pragma unroll
        for (int q = 0; q < 4; q++) {
            int off = (wid * 4 + q) * 1024;      // wave-uniform dest (in tile)
            int F = off + lane * 16;             // this lane's dest byte
            int cc = F >> 8;                     // dest col within tile
            int s = (F >> 4) & 15;               // dest granule slot
            int srcg = s ^ (cc & 15);            // swizzled source granule
            __builtin_amdgcn_global_load_lds(
                (const __attribute__((address_space(1))) unsigned int*)(Bg + cc * 256 + (srcg << 4)),
                (__attribute__((address_space(3))) unsigned int*)(&Bs[buf][0] + off),
                16, 0, 0);
        }
    };

    dmaB(0, 0);
    // ---- A panel: 64 rows x K=256 in 64 VGPRs (linear, 32 B/lane/block)
    i32x8 apan[4][2];
    {
        const unsigned char* Ag = X + (size_t)row0 * 256;
#pragma unroll
        for (int mi = 0; mi < 4; mi++)
#pragma unroll
            for (int kb = 0; kb < 2; kb++)
                apan[mi][kb] = *(const i32x8*)(Ag + (mi * 16 + l15) * 256 + kb * 128 + l4 * 32);
    }
    dmaB(1, 1);
    __syncthreads();             // one-time full drain: tile0, tile1, A, bias

    float PS[4][4] = {};
    int bc = 0, bp = 2;          // current / dma-target buffer indices

#pragma unroll 1
    for (int it = 0; it < NIT; it++) {
        // tile it+1 (issued one full iteration ago) retires ~free; barrier
        // THEN dma keeps the buffer-reuse WAR ordered.
        asm volatile("s_waitcnt vmcnt(0)" ::: "memory");
        __builtin_amdgcn_s_barrier();
        if (it + 2 < NIT) dmaB(bp, it + 2);
        const unsigned char* bufC = &Bs[bc][0];
        float bl[4];
#pragma unroll
        for (int ni = 0; ni < 4; ni++)
            bl[ni] = biasL[it * 128 + ch * 64 + ni * 16 + l15];
        f32x4 acc[4][4] = {};
        i32x4 br[8];
        __builtin_amdgcn_s_setprio(1);
        // ---- kb = 0: 8 reads, 16 MFMAs
        RD8(bufC, 0, br);
        MF4(0, 0, br); MF4(0, 1, br); MF4(0, 2, br); MF4(0, 3, br);
        // ---- kb = 1: 8 reads (reuse br), then per-ni MFMAs + interleaved
        //      epilogue: exp2(ni) runs on trans pipe while MFMAs(ni+1) run
        //      on the matrix pipe.
        RD8(bufC, 1, br);
        MF4(1, 0, br);
        MF4(1, 1, br); EPI(0);
        MF4(1, 2, br); EPI(1);
        MF4(1, 3, br); EPI(2);
        __builtin_amdgcn_s_setprio(0);
        EPI(3);
        bc = (bc == 2) ? 0 : bc + 1;
        bp = (bp == 2) ? 0 : bp + 1;
    }
    // ---- one butterfly + atomics per wave ----
#pragma unroll
    for (int mi = 0; mi < 4; mi++)
#pragma unroll
        for (int r = 0; r < 4; r++) {
            float v = PS[mi][r];
            v += __shfl_xor(v, 1); v += __shfl_xor(v, 2);
            v += __shfl_xor(v, 4); v += __shfl_xor(v, 8);
            if (l15 == 0)
                atomicAdd(&rowsum[row0 + mi * 16 + l4 * 4 + r], v);
        }
}

// ---------------------------------------------------------------------------
// K4: build tables in LDS + CKY DP. 16 blocks (one per batch), 1024 thr,
// 16 lanes per (i) cell parallelize the split loop.
// ---------------------------------------------------------------------------
__global__ __launch_bounds__(1024) void dp_kernel(const float* __restrict__ tlog,
                          const float* __restrict__ glog,
                          const float* __restrict__ rowsum,
                          float* __restrict__ out) {
    __shared__ float Tl[1600], SHWl[1600], REl[1600];
    const int t = threadIdx.x;
    const int b = blockIdx.x;
    const float NEGINF = -__builtin_inff();
    for (int idx = t; idx < 1600; idx += 1024) {
        Tl[idx] = NEGINF; SHWl[idx] = NEGINF; REl[idx] = NEGINF;
    }
    __syncthreads();
    for (int p = t; p < NPAIR; p += 1024) {
        int i = 0, rem = p, len = L_SEQ - 1;
        while (rem >= len) { rem -= len; len--; i++; }
        int j = i + 1 + rem;
        int row = p * 16 + b;
        float tl = tlog[row];
        float re_v = (tl >= 0.f) ? -log1pf(__expf(-tl)) : (tl - log1pf(__expf(tl)));
        float sh_v = (tl <= 0.f) ? -log1pf(__expf(tl)) : (-tl - log1pf(__expf(-tl)));
        float wlp = glog[row] - __logf(rowsum[row]);
        SHWl[i * 40 + j] = sh_v + wlp;
        REl[i * 40 + j] = re_v;
    }
    if (t == 0) {
        int row = NPAIR * 16 + b;           // init cell
        Tl[0 * 40 + 1] = glog[row] - __logf(rowsum[row]);
    }
    if (t >= 1 && t <= 38) Tl[t * 40 + t + 1] = 0.f;
    __syncthreads();
    const int tg = t >> 4, li = t & 15;
    for (int gap = 2; gap <= L_SEQ - 1; gap++) {
        int n_i = L_SEQ - gap;
        float m = NEGINF, s = 0.f;
        int i = tg, j = tg + gap;
        if (tg < n_i) {
            for (int k = i + 1 + li; k < j; k += 16) {
                float v = Tl[i * 40 + k] + Tl[k * 40 + j]
                        + SHWl[i * 40 + k] + REl[k * 40 + j];
                if (v > m) { s = s * __expf(m - v) + 1.f; m = v; }
                else s += __expf(v - m);
            }
        }
#pragma unroll
        for (int off = 1; off < 16; off <<= 1) {
            float mo = __shfl_xor(m, off), so = __shfl_xor(s, off);
            float M = fmaxf(m, mo);
            float sn = 0.f;
            if (m > NEGINF) sn += s * __expf(m - M);
            if (mo > NEGINF) sn += so * __expf(mo - M);
            m = M; s = sn;
        }
        if (tg < n_i && li == 0) Tl[i * 40 + j] = m + __logf(s);
        __syncthreads();
    }
    if (t == 0) out[b] = Tl[39];
}

// ---------------------------------------------------------------------------
extern "C" void kernel_launch(void* const* d_in, const int* in_sizes, int n_in,
                              void* d_out, int out_size, void* d_ws, size_t ws_size,
                              hipStream_t stream) {
    const float* h        = (const float*)d_in[0];
    const int*   sentence = (const int*)d_in[1];
    const float* Wt1      = (const float*)d_in[2];
    const float* bt1      = (const float*)d_in[3];
    const float* Wt2      = (const float*)d_in[4];
    const float* bt2      = (const float*)d_in[5];
    const float* Ww1      = (const float*)d_in[6];
    const float* bw1      = (const float*)d_in[7];
    const float* Ww2      = (const float*)d_in[8];
    const float* bw2      = (const float*)d_in[9];
    float* out = (float*)d_out;

    char* ws = (char*)d_ws;
    size_t off = 0;
    float* UV = (float*)(ws + off);                    off += 4ull * 640 * 256 * 4;
    unsigned char* X = (unsigned char*)(ws + off);     off += (size_t)M_ROWS * 256;
    unsigned char* WbT = (unsigned char*)(ws + off);   off += (size_t)V_PAD * 256;
    float* WwT = (float*)(ws + off);                   off += (size_t)V_PAD * 256 * 4;
    float* rowsum = (float*)(ws + off);                off += (size_t)M_ROWS * 4;
    float* tlog = (float*)(ws + off);                  off += (size_t)M_ROWS * 4;
    float* glog = (float*)(ws + off);                  off += (size_t)M_ROWS * 4;

    hipMemsetAsync(rowsum, 0, (size_t)M_ROWS * 4, stream);
    hipMemsetAsync(UV, 0, 4ull * 640 * 256 * 4, stream);
    prep_kernel<<<1920, 256, 0, stream>>>(Ww2, WwT, WbT, h, Wt1, Ww1, UV);
    build_rows<<<M_ROWS / 4, 256, 0, stream>>>(UV, sentence, bt1, bw1, Wt2, bt2,
                                               WwT, bw2, X, tlog, glog);
    big_gemm<<<dim3(5, 49), 512, 0, stream>>>(X, WbT, bw2, rowsum);
    dp_kernel<<<16, 1024, 0, stream>>>(tlog, glog, rowsum, out);
}